// Round 2
// baseline (856.228 us; speedup 1.0000x reference)
//
#include <hip/hip_runtime.h>
#include <cstdint>
#include <cstddef>

// Problem constants
#define LSEQ 2048
#define NB   2      // batch
#define CCH  1024   // channels
#define NHD  16     // heads
#define HDD  64     // head dim
#define FFC  4096   // conv hidden
#define KW   9      // conv kernel width
#define MROWS 4096  // L*B

typedef __bf16 bf16x8 __attribute__((ext_vector_type(8)));
typedef float  floatx4 __attribute__((ext_vector_type(4)));
typedef unsigned short ushort4v __attribute__((ext_vector_type(4)));

__device__ inline unsigned short f2bf(float f) {
  union { float f; unsigned u; } v; v.f = f;
  unsigned r = v.u + 0x7FFFu + ((v.u >> 16) & 1u);
  return (unsigned short)(r >> 16);
}

// async global->LDS, 16B per lane. Dest must be wave-uniform base + lane*16.
__device__ inline void gload_lds16(const unsigned short* g, unsigned short* l) {
  __builtin_amdgcn_global_load_lds(
      (__attribute__((address_space(1))) unsigned int*)(g),
      (__attribute__((address_space(3))) unsigned int*)(l), 16, 0, 0);
}

// ---------------- element-wise converts ----------------
__global__ void f2bf4_kernel(const float* __restrict__ in, unsigned short* __restrict__ out, int n4) {
  int idx = blockIdx.x * 256 + threadIdx.x;
  if (idx >= n4) return;
  const floatx4 v = ((const floatx4*)in)[idx];
  unsigned long long pk = (unsigned long long)f2bf(v[0]) |
                          ((unsigned long long)f2bf(v[1]) << 16) |
                          ((unsigned long long)f2bf(v[2]) << 32) |
                          ((unsigned long long)f2bf(v[3]) << 48);
  ((unsigned long long*)out)[idx] = pk;
}

// conv1_w (FF, C, K) fp32 -> w1p[f*9216 + k*1024 + c] bf16.
__global__ __launch_bounds__(256) void repack_w1_kernel(const float* __restrict__ in,
                                                        unsigned short* __restrict__ out) {
  __shared__ unsigned short t[9216];
  const int f = blockIdx.x, tid = threadIdx.x;
  const float* src = in + (size_t)f * 9216;
#pragma unroll
  for (int rnd = 0; rnd < 9; ++rnd) {
    const int p = (rnd * 256 + tid) * 4;
    const floatx4 v = *(const floatx4*)(src + p);
#pragma unroll
    for (int e = 0; e < 4; ++e) {
      const int idx = p + e;
      const int c = idx / 9, k = idx - c * 9;
      t[k * 1024 + c] = f2bf(v[e]);
    }
  }
  __syncthreads();
  unsigned short* dst = out + (size_t)f * 9216;
#pragma unroll
  for (int rnd = 0; rnd < 9; ++rnd) {
    const int j = (rnd * 256 + tid) * 4;
    *(ushort4v*)(dst + j) = *(const ushort4v*)&t[j];
  }
}

__global__ void zero_u16(unsigned short* p, int n) {
  int idx = blockIdx.x * 256 + threadIdx.x;
  if (idx < n) p[idx] = 0;
}

// V [bh][l][d] -> V^T [bh][d][l].  64x64 tile per block, LDS transpose,
// coalesced 8B on both sides.
__global__ __launch_bounds__(256) void transpose_v_kernel(
    const unsigned short* __restrict__ vin, unsigned short* __restrict__ vout) {
  __shared__ unsigned short t[64][65];
  const int tid = threadIdx.x;
  const int l0 = blockIdx.x * 64, bh = blockIdx.y;
  const unsigned short* src = vin + ((size_t)bh * LSEQ + l0) * HDD;
  const int rr = tid >> 4, cc = (tid & 15) * 4;
#pragma unroll
  for (int rnd = 0; rnd < 4; ++rnd) {
    const int row = rnd * 16 + rr;
    const ushort4v v = *(const ushort4v*)(src + row * HDD + cc);
#pragma unroll
    for (int e = 0; e < 4; ++e) t[row][cc + e] = v[e];
  }
  __syncthreads();
  unsigned short* dst = vout + (size_t)bh * HDD * LSEQ + l0;
#pragma unroll
  for (int rnd = 0; rnd < 4; ++rnd) {
    const int drow = rnd * 16 + rr;
    ushort4v v;
#pragma unroll
    for (int e = 0; e < 4; ++e) v[e] = t[cc + e][drow];
    *(ushort4v*)(dst + (size_t)drow * LSEQ + cc) = v;
  }
}

// ---------------- GEMM: C = A(MxK) * B(NxK)^T + bias ----------------
// 128xBN tile, BK=32, 4 waves, 16x16x32 bf16 MFMA, global_load_lds width=16,
// XOR swizzle (0 conflicts).  Used for QKV / out-proj / conv2.
template <int EPI, bool KDEC, int BN>
__global__ __launch_bounds__(256) void gemm_bt(
    const unsigned short* __restrict__ A, const unsigned short* __restrict__ Bm,
    const float* __restrict__ bias, int N, int Kstride, int Klen,
    float* __restrict__ outF, float* __restrict__ outF2,
    unsigned short* __restrict__ outB,
    unsigned short* __restrict__ qb, unsigned short* __restrict__ kb,
    unsigned short* __restrict__ vb) {
  constexpr int JN = BN / 32;  // j-fragments per wave
  __shared__ alignas(16) unsigned short lA[128 * 32];
  __shared__ alignas(16) unsigned short lB[BN * 32];
  const int tid = threadIdx.x;
  const int m0 = blockIdx.x * 128;
  const int n0 = blockIdx.y * BN;
  const int z = blockIdx.z;
  A += (size_t)z * Klen;
  Bm += (size_t)z * Klen;
  const int wave = tid >> 6, lane = tid & 63;
  const int wm = (wave >> 1) * 64, wn = (wave & 1) * (BN / 2);
  const int l16 = lane & 15, quad = lane >> 4;
  const int fsw = (quad ^ ((l16 >> 1) & 3)) << 3;

  size_t aoff[2], boff[BN / 64];
#pragma unroll
  for (int i = 0; i < 2; ++i) {
    const int cf = i * 256 + tid;
    const int row = cf >> 2, cs = cf & 3;
    const int col = ((cs ^ ((row >> 1) & 3)) << 3);
    aoff[i] = (KDEC ? (size_t)row * 1024 : (size_t)(m0 + row) * Kstride) + col;
  }
#pragma unroll
  for (int i = 0; i < BN / 64; ++i) {
    const int cf = i * 256 + tid;
    const int row = cf >> 2, cs = cf & 3;
    const int col = ((cs ^ ((row >> 1) & 3)) << 3);
    boff[i] = (size_t)(n0 + row) * Kstride + col;
  }

  floatx4 acc[4][JN];
#pragma unroll
  for (int i = 0; i < 4; ++i)
#pragma unroll
    for (int j = 0; j < JN; ++j) acc[i][j] = (floatx4){0.f, 0.f, 0.f, 0.f};

  auto kstep = [&](const unsigned short* Ab, const unsigned short* Bb) {
    __syncthreads();
#pragma unroll
    for (int i = 0; i < 2; ++i)
      gload_lds16(Ab + aoff[i], &lA[(i * 256 + tid) * 8]);
#pragma unroll
    for (int i = 0; i < BN / 64; ++i)
      gload_lds16(Bb + boff[i], &lB[(i * 256 + tid) * 8]);
    __syncthreads();
    bf16x8 af[4], bf[JN];
#pragma unroll
    for (int i = 0; i < 4; ++i)
      af[i] = *(const bf16x8*)&lA[(wm + i * 16 + l16) * 32 + fsw];
#pragma unroll
    for (int j = 0; j < JN; ++j)
      bf[j] = *(const bf16x8*)&lB[(wn + j * 16 + l16) * 32 + fsw];
#pragma unroll
    for (int i = 0; i < 4; ++i)
#pragma unroll
      for (int j = 0; j < JN; ++j)
        acc[i][j] = __builtin_amdgcn_mfma_f32_16x16x32_bf16(af[i], bf[j], acc[i][j], 0, 0, 0);
  };

  if (KDEC) {
    for (int seg = 0; seg < KW; ++seg) {
      const unsigned short* Ab = A + (size_t)(m0 + seg * NB) * 1024;
      const unsigned short* Bb = Bm + seg * 1024;
      for (int kk = 0; kk < 1024; kk += 32) kstep(Ab + kk, Bb + kk);
    }
  } else {
    for (int k0 = 0; k0 < Klen; k0 += 32) kstep(A + k0, Bm + k0);
  }

  float* outZ = (z == 0) ? outF : outF2;
#pragma unroll
  for (int i = 0; i < 4; ++i) {
#pragma unroll
    for (int j = 0; j < JN; ++j) {
      const int colg = n0 + wn + j * 16 + l16;
      const int rbase = m0 + wm + i * 16 + quad * 4;
      const float bv = bias ? bias[colg] : 0.f;
      float vv[4];
#pragma unroll
      for (int r = 0; r < 4; ++r) vv[r] = acc[i][j][r] + bv;
      if (EPI == 1) {
#pragma unroll
        for (int r = 0; r < 4; ++r) outZ[(size_t)(rbase + r) * N + colg] = vv[r];
      } else if (EPI == 2) {
#pragma unroll
        for (int r = 0; r < 4; ++r)
          outB[(size_t)(rbase + r) * N + colg] = f2bf(fmaxf(vv[r], 0.f));
      } else {
        const int seg = colg >> 10;  // 0:q 1:k 2:v
        const int c = colg & 1023, h = c >> 6, d = c & 63;
        unsigned short* dst = (seg == 0) ? qb : (seg == 1) ? kb : vb;
        const float scl = (seg == 0) ? 0.125f : 1.f;
#pragma unroll
        for (int r = 0; r < 4; ++r) {
          const int row = rbase + r, l = row >> 1, b = row & 1;
          dst[(((size_t)(b * NHD + h)) * LSEQ + l) * HDD + d] = f2bf(vv[r] * scl);
        }
      }
    }
  }
}

// ---------------- conv1 as 256x256 8-phase GEMM ----------------
// out[m][f] = relu( sum_{seg,c} x1p[(m+seg*2)*1024+c] * w1p[f*9216+seg*1024+c] + b1[f] )
// M=N=4096, K=9216 (144 K-tiles of BK=64).  8 waves (2Mx4N), 512 thr.
// LDS 128 KiB: per matrix 2 buf x 2 khalf regions of [256 rows][32 K] bf16.
// Phase pairing: odd phase (rh0) loads bf fresh + af; even phase (rh1)
// reuses bf from registers (B fragments identical across rh) -> LDS read
// traffic drops 512->384 KB per iteration (the distinct-fragment minimum
// for the 2Mx4N wave grid).
// Waitcnt discipline: NO leading lgkmcnt(0) -- the compiler inserts
// fine-grained per-operand lgkmcnt before each MFMA use, so early MFMAs
// overlap the LDS read tail.  A TRAILING lgkmcnt(0) (merged with the vmcnt
// wait where present) guarantees this phase's in-flight ds_reads complete
// before the closing barrier publishes the region for re-staging (the
// region read at phase p is overwritten by a stage in phase p+1).
// Pure-compiler fences (asm "" memory) bracket each phase's memory ops so
// reads/stages cannot migrate across barriers.
// Stage schedule / vmcnt cadence identical to the verified pipeline:
//   p1..p8 stage 1 unit each: A[T+1]k1, B[T+1]k1, A[T+2]k0, B[T+2]k0,
//                             A[T+2]k1, B[T+2]k1, A[T+3]k0, B[T+3]k0
//   vmcnt(8) at even phases = 4 units in flight; a region staged at phase p
//   is forced complete >= 1 barrier before its first read (5-phase latency
//   budget ~ 2000 cy >> 900 cy HBM miss latency).
#define WL   "s_waitcnt lgkmcnt(0)"
#define WV8L "s_waitcnt vmcnt(8) lgkmcnt(0)"
#define WV4L "s_waitcnt vmcnt(4) lgkmcnt(0)"
#define WV0L "s_waitcnt vmcnt(0) lgkmcnt(0)"
#define NOSTAGE ((void)0)

#define PH_CORE(p, kh, rh, LOADB, STAGE, WAITSTR) do {                         \
    asm volatile("" ::: "memory");                                             \
    const unsigned short* Ar_ = &lA[((p) * 2 + (kh)) * 8192];                  \
    if (LOADB) {                                                               \
      const unsigned short* Br_ = &lB[((p) * 2 + (kh)) * 8192];                \
      _Pragma("unroll")                                                        \
      for (int j_ = 0; j_ < 4; ++j_)                                           \
        bfc[j_] = *(const bf16x8*)&Br_[(wn * 64 + j_ * 16 + l16) * 32 + fsw];  \
    }                                                                          \
    bf16x8 af_[4];                                                             \
    _Pragma("unroll")                                                          \
    for (int i_ = 0; i_ < 4; ++i_)                                             \
      af_[i_] = *(const bf16x8*)&Ar_[(wm * 128 + (rh) * 64 + i_ * 16 + l16) * 32 + fsw]; \
    STAGE;                                                                     \
    asm volatile("" ::: "memory");                                             \
    __builtin_amdgcn_s_barrier();                                              \
    __builtin_amdgcn_s_setprio(1);                                             \
    _Pragma("unroll")                                                          \
    for (int i_ = 0; i_ < 4; ++i_)                                             \
      _Pragma("unroll")                                                        \
      for (int j_ = 0; j_ < 4; ++j_)                                           \
        acc[(rh) * 4 + i_][j_] = __builtin_amdgcn_mfma_f32_16x16x32_bf16(      \
            af_[i_], bfc[j_], acc[(rh) * 4 + i_][j_], 0, 0, 0);                \
    __builtin_amdgcn_s_setprio(0);                                             \
    asm volatile(WAITSTR ::: "memory");                                        \
    __builtin_amdgcn_s_barrier();                                              \
  } while (0)

__global__ __launch_bounds__(512, 2) void gemm256_conv1(
    const unsigned short* __restrict__ A,   // x1p base (4112 rows x 1024)
    const unsigned short* __restrict__ Bm,  // w1p (4096 x 9216)
    const float* __restrict__ bias,         // b1
    unsigned short* __restrict__ outB) {    // hbuf (4096 x 4096)
  __shared__ alignas(16) unsigned short lA[4 * 8192];  // [buf][kh][256][32]
  __shared__ alignas(16) unsigned short lB[4 * 8192];
  const int tid = threadIdx.x;
  const int m0 = blockIdx.x * 256, n0 = blockIdx.y * 256;
  const int wave = tid >> 6, lane = tid & 63;
  const int wm = wave >> 2, wn = wave & 3;        // 2 x 4 wave grid
  const int l16 = lane & 15, quad = lane >> 4;
  const int fsw = (quad ^ ((l16 >> 1) & 3)) << 3;

  // per-thread staging base offsets (elements), swizzled col
  unsigned int aoff[2], boff[2];
#pragma unroll
  for (int i = 0; i < 2; ++i) {
    const int cf = i * 512 + tid;
    const int row = cf >> 2, cs = cf & 3;
    const int col = (cs ^ ((row >> 1) & 3)) << 3;
    aoff[i] = (unsigned)(m0 + row) * 1024u + (unsigned)col;
    boff[i] = (unsigned)(n0 + row) * 9216u + (unsigned)col;
  }

  floatx4 acc[8][4];
#pragma unroll
  for (int i = 0; i < 8; ++i)
#pragma unroll
    for (int j = 0; j < 4; ++j) acc[i][j] = (floatx4){0.f, 0.f, 0.f, 0.f};
  bf16x8 bfc[4];  // B fragments, reused across the rh pair

  // stage one khalf region (2 x global_load_lds dwordx4 per thread)
  auto stA = [&](int t, int kh) {
    const int p = t & 1;
    const unsigned koff = (unsigned)(t >> 4) * 2048u + (unsigned)((t & 15) * 64 + kh * 32);
#pragma unroll
    for (int i = 0; i < 2; ++i)
      gload_lds16(A + aoff[i] + koff, &lA[(p * 2 + kh) * 8192 + (i * 512 + tid) * 8]);
  };
  auto stB = [&](int t, int kh) {
    const int p = t & 1;
    const unsigned koff = (unsigned)t * 64u + (unsigned)(kh * 32);
#pragma unroll
    for (int i = 0; i < 2; ++i)
      gload_lds16(Bm + boff[i] + koff, &lB[(p * 2 + kh) * 8192 + (i * 512 + tid) * 8]);
  };

  // prologue: tile0 (both khalves) + tile1 kh0 -> 12 loads; wait 4 oldest
  stA(0, 0); stB(0, 0); stA(0, 1); stB(0, 1); stA(1, 0); stB(1, 0);
  asm volatile("s_waitcnt vmcnt(8)" ::: "memory");
  __builtin_amdgcn_s_barrier();

  const int NIT = 72;  // 144 K-tiles / 2 per iteration
  for (int it = 0; it < NIT - 1; ++it) {
    const int T = it * 2;
    PH_CORE(0, 0, 0, 1, stA(T + 1, 1), WL);
    PH_CORE(0, 0, 1, 0, stB(T + 1, 1), WV8L);
    PH_CORE(0, 1, 0, 1, stA(T + 2, 0), WL);
    PH_CORE(0, 1, 1, 0, stB(T + 2, 0), WV8L);
    PH_CORE(1, 0, 0, 1, stA(T + 2, 1), WL);
    PH_CORE(1, 0, 1, 0, stB(T + 2, 1), WV8L);
    PH_CORE(1, 1, 0, 1, stA(T + 3, 0), WL);
    PH_CORE(1, 1, 1, 0, stB(T + 3, 0), WV8L);
  }
  {  // last iteration: no prefetch beyond tile NT-1; de-rate waits
    const int T = (NIT - 1) * 2;
    PH_CORE(0, 0, 0, 1, stA(T + 1, 1), WL);
    PH_CORE(0, 0, 1, 0, stB(T + 1, 1), WV8L);
    PH_CORE(0, 1, 0, 1, NOSTAGE, WL);
    PH_CORE(0, 1, 1, 0, NOSTAGE, WV4L);
    PH_CORE(1, 0, 0, 1, NOSTAGE, WL);
    PH_CORE(1, 0, 1, 0, NOSTAGE, WV0L);
    PH_CORE(1, 1, 0, 1, NOSTAGE, WL);
    PH_CORE(1, 1, 1, 0, NOSTAGE, WL);
  }

  // epilogue: row = m0 + wm*128 + ii*16 + quad*4 + r, col = n0 + wn*64 + j*16 + l16
#pragma unroll
  for (int ii = 0; ii < 8; ++ii) {
#pragma unroll
    for (int j = 0; j < 4; ++j) {
      const int colg = n0 + wn * 64 + j * 16 + l16;
      const int rbase = m0 + wm * 128 + ii * 16 + quad * 4;
      const float bv = bias[colg];
#pragma unroll
      for (int r = 0; r < 4; ++r)
        outB[(size_t)(rbase + r) * FFC + colg] = f2bf(fmaxf(acc[ii][j][r] + bv, 0.f));
    }
  }
}

// ---------------- flash attention ----------------
__global__ __launch_bounds__(256) void attn_kernel(
    const unsigned short* __restrict__ qg, const unsigned short* __restrict__ kg,
    const unsigned short* __restrict__ vtg, unsigned short* __restrict__ ao) {
  __shared__ alignas(16) unsigned short lK[64 * 64];   // [key][d] swizzled
  __shared__ alignas(16) unsigned short lV[64 * 64];   // [d][key] swizzled
  __shared__ alignas(16) unsigned short lP[4][16 * 64];
  const int tid = threadIdx.x;
  const int wave = tid >> 6, lane = tid & 63;
  const int l16 = lane & 15, quad = lane >> 4;
  const int sw0 = ((quad ^ (l16 & 7)) << 3);
  const int sw1 = (((quad | 4) ^ (l16 & 7)) << 3);
  const int qt = blockIdx.x, h = blockIdx.y, b = blockIdx.z;
  const unsigned short* Q = qg + ((size_t)(b * NHD + h) * LSEQ) * HDD;
  const unsigned short* Kp = kg + ((size_t)(b * NHD + h) * LSEQ) * HDD;
  const unsigned short* Vt = vtg + ((size_t)(b * NHD + h) * HDD) * LSEQ;
  const int q0 = qt * 64 + wave * 16;

  const bf16x8 qa0 = *(const bf16x8*)&Q[(size_t)(q0 + l16) * HDD + quad * 8];
  const bf16x8 qa1 = *(const bf16x8*)&Q[(size_t)(q0 + l16) * HDD + 32 + quad * 8];

  float mr[4], lr[4];
  floatx4 o[4];
#pragma unroll
  for (int r = 0; r < 4; ++r) { mr[r] = -1e30f; lr[r] = 0.f; }
#pragma unroll
  for (int nb = 0; nb < 4; ++nb) o[nb] = (floatx4){0.f, 0.f, 0.f, 0.f};

  for (int kt = 0; kt < LSEQ; kt += 64) {
    __syncthreads();
#pragma unroll
    for (int i = 0; i < 2; ++i) {
      const int flat = i * 256 + tid;
      const int row = flat >> 3, cs = flat & 7;
      const int col = ((cs ^ (row & 7)) << 3);
      gload_lds16(&Kp[(size_t)(kt + row) * HDD + col], &lK[flat * 8]);
      gload_lds16(&Vt[(size_t)row * LSEQ + kt + col], &lV[flat * 8]);
    }
    __syncthreads();
    floatx4 s[4];
#pragma unroll
    for (int nb = 0; nb < 4; ++nb) {
      const bf16x8 kf0 = *(const bf16x8*)&lK[(nb * 16 + l16) * 64 + sw0];
      const bf16x8 kf1 = *(const bf16x8*)&lK[(nb * 16 + l16) * 64 + sw1];
      floatx4 t = (floatx4){0.f, 0.f, 0.f, 0.f};
      t = __builtin_amdgcn_mfma_f32_16x16x32_bf16(qa0, kf0, t, 0, 0, 0);
      t = __builtin_amdgcn_mfma_f32_16x16x32_bf16(qa1, kf1, t, 0, 0, 0);
      s[nb] = t;
    }
    float mnew[4], alpha[4];
#pragma unroll
    for (int r = 0; r < 4; ++r) {
      float mx = fmaxf(fmaxf(s[0][r], s[1][r]), fmaxf(s[2][r], s[3][r]));
      mx = fmaxf(mx, __shfl_xor(mx, 1));
      mx = fmaxf(mx, __shfl_xor(mx, 2));
      mx = fmaxf(mx, __shfl_xor(mx, 4));
      mx = fmaxf(mx, __shfl_xor(mx, 8));
      mnew[r] = fmaxf(mr[r], mx);
      alpha[r] = __expf(mr[r] - mnew[r]);
      mr[r] = mnew[r];
    }
#pragma unroll
    for (int nb = 0; nb < 4; ++nb)
#pragma unroll
      for (int r = 0; r < 4; ++r) s[nb][r] = __expf(s[nb][r] - mnew[r]);
#pragma unroll
    for (int r = 0; r < 4; ++r) {
      float sm = s[0][r] + s[1][r] + s[2][r] + s[3][r];
      sm += __shfl_xor(sm, 1);
      sm += __shfl_xor(sm, 2);
      sm += __shfl_xor(sm, 4);
      sm += __shfl_xor(sm, 8);
      lr[r] = lr[r] * alpha[r] + sm;
    }
#pragma unroll
    for (int nb = 0; nb < 4; ++nb)
#pragma unroll
      for (int r = 0; r < 4; ++r) {
        const int row = quad * 4 + r;
        const int q = nb * 2 + (l16 >> 3);
        lP[wave][row * 64 + ((q ^ (row & 7)) << 3) + (l16 & 7)] = f2bf(s[nb][r]);
        o[nb][r] *= alpha[r];
      }
    asm volatile("s_waitcnt lgkmcnt(0)" ::: "memory");
    const bf16x8 pa0 = *(const bf16x8*)&lP[wave][l16 * 64 + sw0];
    const bf16x8 pa1 = *(const bf16x8*)&lP[wave][l16 * 64 + sw1];
#pragma unroll
    for (int nb = 0; nb < 4; ++nb) {
      const bf16x8 vf0 = *(const bf16x8*)&lV[(nb * 16 + l16) * 64 + sw0];
      const bf16x8 vf1 = *(const bf16x8*)&lV[(nb * 16 + l16) * 64 + sw1];
      o[nb] = __builtin_amdgcn_mfma_f32_16x16x32_bf16(pa0, vf0, o[nb], 0, 0, 0);
      o[nb] = __builtin_amdgcn_mfma_f32_16x16x32_bf16(pa1, vf1, o[nb], 0, 0, 0);
    }
  }
#pragma unroll
  for (int nb = 0; nb < 4; ++nb)
#pragma unroll
    for (int r = 0; r < 4; ++r) {
      const float v = o[nb][r] / lr[r];
      const int lg = q0 + quad * 4 + r;
      ao[((size_t)lg * NB + b) * CCH + h * HDD + nb * 16 + l16] = f2bf(v);
    }
}

// ---------------- layernorm (+residuals) ----------------
__global__ __launch_bounds__(256) void ln_kernel(
    const float* __restrict__ a, const float* __restrict__ c,
    const float* __restrict__ c2, const float* __restrict__ cbias,
    const float* __restrict__ w, const float* __restrict__ bias,
    float* __restrict__ outF, unsigned short* __restrict__ outB) {
  const int row = blockIdx.x;
  const int tid = threadIdx.x;
  const floatx4 va = *(const floatx4*)(a + (size_t)row * 1024 + tid * 4);
  const floatx4 vc = *(const floatx4*)(c + (size_t)row * 1024 + tid * 4);
  float v0 = va[0] + vc[0], v1 = va[1] + vc[1], v2 = va[2] + vc[2], v3 = va[3] + vc[3];
  if (c2) {
    const floatx4 v2c = *(const floatx4*)(c2 + (size_t)row * 1024 + tid * 4);
    v0 += v2c[0]; v1 += v2c[1]; v2 += v2c[2]; v3 += v2c[3];
  }
  if (cbias) {
    const floatx4 vb = *(const floatx4*)(cbias + tid * 4);
    v0 += vb[0]; v1 += vb[1]; v2 += vb[2]; v3 += vb[3];
  }
  float s = v0 + v1 + v2 + v3;
  float ss = v0 * v0 + v1 * v1 + v2 * v2 + v3 * v3;
#pragma unroll
  for (int off = 1; off < 64; off <<= 1) {
    s += __shfl_xor(s, off);
    ss += __shfl_xor(ss, off);
  }
  __shared__ float red[8];
  const int wave = tid >> 6, lane = tid & 63;
  if (lane == 0) { red[wave] = s; red[4 + wave] = ss; }
  __syncthreads();
  s = red[0] + red[1] + red[2] + red[3];
  ss = red[4] + red[5] + red[6] + red[7];
  const float mu = s * (1.f / 1024.f);
  const float var = ss * (1.f / 1024.f) - mu * mu;
  const float rs = rsqrtf(var + 1e-5f);
  const floatx4 wv = *(const floatx4*)(w + tid * 4);
  const floatx4 bv = *(const floatx4*)(bias + tid * 4);
  const float o0 = (v0 - mu) * rs * wv[0] + bv[0];
  const float o1 = (v1 - mu) * rs * wv[1] + bv[1];
  const float o2 = (v2 - mu) * rs * wv[2] + bv[2];
  const float o3 = (v3 - mu) * rs * wv[3] + bv[3];
  *(floatx4*)(outF + (size_t)row * 1024 + tid * 4) = (floatx4){o0, o1, o2, o3};
  if (outB) {
    unsigned long long pk = (unsigned long long)f2bf(o0) |
                            ((unsigned long long)f2bf(o1) << 16) |
                            ((unsigned long long)f2bf(o2) << 32) |
                            ((unsigned long long)f2bf(o3) << 48);
    *(unsigned long long*)(outB + (size_t)row * 1024 + tid * 4) = pk;
  }
}

extern "C" void kernel_launch(void* const* d_in, const int* in_sizes, int n_in,
                              void* d_out, int out_size, void* d_ws, size_t ws_size,
                              hipStream_t stream) {
  const float* x = (const float*)d_in[0];
  const float* wqkv = (const float*)d_in[2];
  const float* bqkv = (const float*)d_in[3];
  const float* wout = (const float*)d_in[4];
  const float* bout = (const float*)d_in[5];
  const float* w1 = (const float*)d_in[6];
  const float* b1 = (const float*)d_in[7];
  const float* w2 = (const float*)d_in[8];
  const float* b2 = (const float*)d_in[9];
  const float* n1w = (const float*)d_in[10];
  const float* n1b = (const float*)d_in[11];
  const float* n2w = (const float*)d_in[12];
  const float* n2b = (const float*)d_in[13];
  float* out = (float*)d_out;

  char* ws = (char*)d_ws;
  size_t off = 0;
  auto alloc = [&](size_t bytes) -> char* {
    char* p = ws + off;
    off += (bytes + 255) & ~(size_t)255;
    return p;
  };
  unsigned short* xb    = (unsigned short*)alloc((size_t)MROWS * 1024 * 2);   // 8.4 MB
  unsigned short* wqkvb = (unsigned short*)alloc((size_t)3072 * 1024 * 2);    // 6.3 MB
  unsigned short* woutb = (unsigned short*)alloc((size_t)1024 * 1024 * 2);    // 2.1 MB
  unsigned short* w1p   = (unsigned short*)alloc((size_t)FFC * 9216 * 2);
  unsigned short* w2b   = (unsigned short*)alloc((size_t)1024 * FFC * 2);
  unsigned short* qbuf  = (unsigned short*)alloc((size_t)NB * NHD * LSEQ * HDD * 2);
  unsigned short* kbuf  = (unsigned short*)alloc((size_t)NB * NHD * LSEQ * HDD * 2);
  unsigned short* vtbuf = (unsigned short*)alloc((size_t)NB * NHD * LSEQ * HDD * 2);
  unsigned short* ao    = (unsigned short*)alloc((size_t)MROWS * 1024 * 2);
  float*          yz    = (float*)alloc((size_t)MROWS * 1024 * 4);
  float*          x1f   = (float*)alloc((size_t)MROWS * 1024 * 4);
  unsigned short* x1p   = (unsigned short*)alloc((size_t)(LSEQ + 8) * NB * 1024 * 2);
  unsigned short* hbuf  = (unsigned short*)alloc((size_t)MROWS * FFC * 2);
  if (off > ws_size) return;  // workspace too small -> visible failure
  // dead-region aliases (no extra ws):
  float*          yzB   = (float*)xb;
  unsigned short* vbuf  = hbuf;

  int n;
  n = MROWS * 1024 / 4; f2bf4_kernel<<<(n + 255) / 256, 256, 0, stream>>>(x, xb, n);
  n = 3072 * 1024 / 4;  f2bf4_kernel<<<(n + 255) / 256, 256, 0, stream>>>(wqkv, wqkvb, n);
  n = 1024 * 1024 / 4;  f2bf4_kernel<<<(n + 255) / 256, 256, 0, stream>>>(wout, woutb, n);
  n = 1024 * FFC / 4;   f2bf4_kernel<<<(n + 255) / 256, 256, 0, stream>>>(w2, w2b, n);
  repack_w1_kernel<<<FFC, 256, 0, stream>>>(w1, w1p);
  zero_u16<<<32, 256, 0, stream>>>(x1p, 8 * 1024);
  zero_u16<<<32, 256, 0, stream>>>(x1p + (size_t)(LSEQ + 4) * NB * 1024, 8 * 1024);

  // QKV projection (M=4096, N=3072, K=1024); q/k/v all natural [b,h,l,d]
  gemm_bt<0, false, 128><<<dim3(32, 24), 256, 0, stream>>>(
      xb, wqkvb, bqkv, 3072, 1024, 1024, nullptr, nullptr, nullptr, qbuf, kbuf, vbuf);
  // V -> V^T (coalesced LDS transpose)
  transpose_v_kernel<<<dim3(LSEQ / 64, NB * NHD), 256, 0, stream>>>(vbuf, vtbuf);
  // flash attention -> ao (L*B, C) bf16
  attn_kernel<<<dim3(LSEQ / 64, NHD, NB), 256, 0, stream>>>(qbuf, kbuf, vtbuf, ao);
  // out projection (M=4096, N=1024, K=1024) -> yz fp32
  gemm_bt<1, false, 64><<<dim3(32, 16), 256, 0, stream>>>(
      ao, woutb, bout, 1024, 1024, 1024, yz, nullptr, nullptr, nullptr, nullptr, nullptr);
  // LN1: x + yz -> x1f fp32, x1p bf16 (shifted +8 rows for l-padding)
  ln_kernel<<<MROWS, 256, 0, stream>>>(x, yz, nullptr, nullptr, n1w, n1b, x1f, x1p + 8 * 1024);
  // conv1 as 256x256 8-phase GEMM (M=4096, N=4096, K=9216) + bias + relu -> hbuf bf16
  gemm256_conv1<<<dim3(16, 16), 512, 0, stream>>>(x1p, w1p, b1, hbuf);
  // conv2 pointwise (M=4096, N=1024, K=4096) split-K x2 -> yz, yzB (raw, bias in LN2)
  gemm_bt<1, false, 64><<<dim3(32, 16, 2), 256, 0, stream>>>(
      hbuf, w2b, nullptr, 1024, FFC, 2048, yz, yzB, nullptr, nullptr, nullptr, nullptr);
  // LN2: x1f + yz + yzB + b2 -> out fp32
  ln_kernel<<<MROWS, 256, 0, stream>>>(x1f, yz, yzB, b2, n2w, n2b, out, nullptr);
}

// Round 4
// 838.390 us; speedup vs baseline: 1.0213x; 1.0213x over previous
//
#include <hip/hip_runtime.h>
#include <cstdint>
#include <cstddef>

// Problem constants
#define LSEQ 2048
#define NB   2      // batch
#define CCH  1024   // channels
#define NHD  16     // heads
#define HDD  64     // head dim
#define FFC  4096   // conv hidden
#define KW   9      // conv kernel width
#define MROWS 4096  // L*B

typedef __bf16 bf16x8 __attribute__((ext_vector_type(8)));
typedef float  floatx4 __attribute__((ext_vector_type(4)));
typedef unsigned short ushort4v __attribute__((ext_vector_type(4)));

__device__ inline unsigned short f2bf(float f) {
  union { float f; unsigned u; } v; v.f = f;
  unsigned r = v.u + 0x7FFFu + ((v.u >> 16) & 1u);
  return (unsigned short)(r >> 16);
}

// async global->LDS, 16B per lane. Dest must be wave-uniform base + lane*16.
__device__ inline void gload_lds16(const unsigned short* g, unsigned short* l) {
  __builtin_amdgcn_global_load_lds(
      (__attribute__((address_space(1))) unsigned int*)(g),
      (__attribute__((address_space(3))) unsigned int*)(l), 16, 0, 0);
}

// ---------------- element-wise converts ----------------
__global__ void f2bf4_kernel(const float* __restrict__ in, unsigned short* __restrict__ out, int n4) {
  int idx = blockIdx.x * 256 + threadIdx.x;
  if (idx >= n4) return;
  const floatx4 v = ((const floatx4*)in)[idx];
  unsigned long long pk = (unsigned long long)f2bf(v[0]) |
                          ((unsigned long long)f2bf(v[1]) << 16) |
                          ((unsigned long long)f2bf(v[2]) << 32) |
                          ((unsigned long long)f2bf(v[3]) << 48);
  ((unsigned long long*)out)[idx] = pk;
}

// conv1_w (FF, C, K) fp32 -> w1p[f*9216 + k*1024 + c] bf16.
__global__ __launch_bounds__(256) void repack_w1_kernel(const float* __restrict__ in,
                                                        unsigned short* __restrict__ out) {
  __shared__ unsigned short t[9216];
  const int f = blockIdx.x, tid = threadIdx.x;
  const float* src = in + (size_t)f * 9216;
#pragma unroll
  for (int rnd = 0; rnd < 9; ++rnd) {
    const int p = (rnd * 256 + tid) * 4;
    const floatx4 v = *(const floatx4*)(src + p);
#pragma unroll
    for (int e = 0; e < 4; ++e) {
      const int idx = p + e;
      const int c = idx / 9, k = idx - c * 9;
      t[k * 1024 + c] = f2bf(v[e]);
    }
  }
  __syncthreads();
  unsigned short* dst = out + (size_t)f * 9216;
#pragma unroll
  for (int rnd = 0; rnd < 9; ++rnd) {
    const int j = (rnd * 256 + tid) * 4;
    *(ushort4v*)(dst + j) = *(const ushort4v*)&t[j];
  }
}

__global__ void zero_u16(unsigned short* p, int n) {
  int idx = blockIdx.x * 256 + threadIdx.x;
  if (idx < n) p[idx] = 0;
}

// V [bh][l][d] -> V^T [bh][d][l].  64x64 tile per block, LDS transpose,
// coalesced 8B on both sides.
__global__ __launch_bounds__(256) void transpose_v_kernel(
    const unsigned short* __restrict__ vin, unsigned short* __restrict__ vout) {
  __shared__ unsigned short t[64][65];
  const int tid = threadIdx.x;
  const int l0 = blockIdx.x * 64, bh = blockIdx.y;
  const unsigned short* src = vin + ((size_t)bh * LSEQ + l0) * HDD;
  const int rr = tid >> 4, cc = (tid & 15) * 4;
#pragma unroll
  for (int rnd = 0; rnd < 4; ++rnd) {
    const int row = rnd * 16 + rr;
    const ushort4v v = *(const ushort4v*)(src + row * HDD + cc);
#pragma unroll
    for (int e = 0; e < 4; ++e) t[row][cc + e] = v[e];
  }
  __syncthreads();
  unsigned short* dst = vout + (size_t)bh * HDD * LSEQ + l0;
#pragma unroll
  for (int rnd = 0; rnd < 4; ++rnd) {
    const int drow = rnd * 16 + rr;
    ushort4v v;
#pragma unroll
    for (int e = 0; e < 4; ++e) v[e] = t[cc + e][drow];
    *(ushort4v*)(dst + (size_t)drow * LSEQ + cc) = v;
  }
}

// ---------------- GEMM: C = A(MxK) * B(NxK)^T + bias ----------------
// 128xBN tile, BK=32, 4 waves, 16x16x32 bf16 MFMA, global_load_lds width=16,
// XOR swizzle (0 conflicts).  Used for QKV / out-proj / conv2.
template <int EPI, bool KDEC, int BN>
__global__ __launch_bounds__(256) void gemm_bt(
    const unsigned short* __restrict__ A, const unsigned short* __restrict__ Bm,
    const float* __restrict__ bias, int N, int Kstride, int Klen,
    float* __restrict__ outF, float* __restrict__ outF2,
    unsigned short* __restrict__ outB,
    unsigned short* __restrict__ qb, unsigned short* __restrict__ kb,
    unsigned short* __restrict__ vb) {
  constexpr int JN = BN / 32;  // j-fragments per wave
  __shared__ alignas(16) unsigned short lA[128 * 32];
  __shared__ alignas(16) unsigned short lB[BN * 32];
  const int tid = threadIdx.x;
  const int m0 = blockIdx.x * 128;
  const int n0 = blockIdx.y * BN;
  const int z = blockIdx.z;
  A += (size_t)z * Klen;
  Bm += (size_t)z * Klen;
  const int wave = tid >> 6, lane = tid & 63;
  const int wm = (wave >> 1) * 64, wn = (wave & 1) * (BN / 2);
  const int l16 = lane & 15, quad = lane >> 4;
  const int fsw = (quad ^ ((l16 >> 1) & 3)) << 3;

  size_t aoff[2], boff[BN / 64];
#pragma unroll
  for (int i = 0; i < 2; ++i) {
    const int cf = i * 256 + tid;
    const int row = cf >> 2, cs = cf & 3;
    const int col = ((cs ^ ((row >> 1) & 3)) << 3);
    aoff[i] = (KDEC ? (size_t)row * 1024 : (size_t)(m0 + row) * Kstride) + col;
  }
#pragma unroll
  for (int i = 0; i < BN / 64; ++i) {
    const int cf = i * 256 + tid;
    const int row = cf >> 2, cs = cf & 3;
    const int col = ((cs ^ ((row >> 1) & 3)) << 3);
    boff[i] = (size_t)(n0 + row) * Kstride + col;
  }

  floatx4 acc[4][JN];
#pragma unroll
  for (int i = 0; i < 4; ++i)
#pragma unroll
    for (int j = 0; j < JN; ++j) acc[i][j] = (floatx4){0.f, 0.f, 0.f, 0.f};

  auto kstep = [&](const unsigned short* Ab, const unsigned short* Bb) {
    __syncthreads();
#pragma unroll
    for (int i = 0; i < 2; ++i)
      gload_lds16(Ab + aoff[i], &lA[(i * 256 + tid) * 8]);
#pragma unroll
    for (int i = 0; i < BN / 64; ++i)
      gload_lds16(Bb + boff[i], &lB[(i * 256 + tid) * 8]);
    __syncthreads();
    bf16x8 af[4], bf[JN];
#pragma unroll
    for (int i = 0; i < 4; ++i)
      af[i] = *(const bf16x8*)&lA[(wm + i * 16 + l16) * 32 + fsw];
#pragma unroll
    for (int j = 0; j < JN; ++j)
      bf[j] = *(const bf16x8*)&lB[(wn + j * 16 + l16) * 32 + fsw];
#pragma unroll
    for (int i = 0; i < 4; ++i)
#pragma unroll
      for (int j = 0; j < JN; ++j)
        acc[i][j] = __builtin_amdgcn_mfma_f32_16x16x32_bf16(af[i], bf[j], acc[i][j], 0, 0, 0);
  };

  if (KDEC) {
    for (int seg = 0; seg < KW; ++seg) {
      const unsigned short* Ab = A + (size_t)(m0 + seg * NB) * 1024;
      const unsigned short* Bb = Bm + seg * 1024;
      for (int kk = 0; kk < 1024; kk += 32) kstep(Ab + kk, Bb + kk);
    }
  } else {
    for (int k0 = 0; k0 < Klen; k0 += 32) kstep(A + k0, Bm + k0);
  }

  float* outZ = (z == 0) ? outF : outF2;
#pragma unroll
  for (int i = 0; i < 4; ++i) {
#pragma unroll
    for (int j = 0; j < JN; ++j) {
      const int colg = n0 + wn + j * 16 + l16;
      const int rbase = m0 + wm + i * 16 + quad * 4;
      const float bv = bias ? bias[colg] : 0.f;
      float vv[4];
#pragma unroll
      for (int r = 0; r < 4; ++r) vv[r] = acc[i][j][r] + bv;
      if (EPI == 1) {
#pragma unroll
        for (int r = 0; r < 4; ++r) outZ[(size_t)(rbase + r) * N + colg] = vv[r];
      } else if (EPI == 2) {
#pragma unroll
        for (int r = 0; r < 4; ++r)
          outB[(size_t)(rbase + r) * N + colg] = f2bf(fmaxf(vv[r], 0.f));
      } else {
        const int seg = colg >> 10;  // 0:q 1:k 2:v
        const int c = colg & 1023, h = c >> 6, d = c & 63;
        unsigned short* dst = (seg == 0) ? qb : (seg == 1) ? kb : vb;
        const float scl = (seg == 0) ? 0.125f : 1.f;
#pragma unroll
        for (int r = 0; r < 4; ++r) {
          const int row = rbase + r, l = row >> 1, b = row & 1;
          dst[(((size_t)(b * NHD + h)) * LSEQ + l) * HDD + d] = f2bf(vv[r] * scl);
        }
      }
    }
  }
}

// ---------------- conv1 as 256x256 4-phase GEMM (1 barrier/phase) --------
// out[m][f] = relu( sum_{seg,c} x1p[(m+seg*2)*1024+c] * w1p[f*9216+seg*1024+c] + b1[f] )
// M=N=4096, K=9216 (144 K-tiles of BK=64).  8 waves (2Mx4N), 512 thr.
// LDS 128 KiB: per matrix 2 buf x 2 khalf regions of [256 rows][32 K] bf16.
//
// Full phase (one khalf) = two halves:
//   half rh0: read bfc[4]+af[4](rows 0-63), stage A-unit, 16 MFMA
//   half rh1: read af[4](rows 64-127) (bfc reused), stage B-unit, 16 MFMA
//   end:      s_waitcnt vmcnt(8) lgkmcnt(0); s_barrier     <- ONLY barrier
// 4 barriers/iteration (was 16).  Waves drift within a phase, so one wave's
// ds_reads co-schedule with another's MFMA (read/MFMA overlap across waves);
// setprio(1) around MFMA arbitrates in favor of the MFMA-issuing wave.
// Correctness invariants preserved:
//  * stage targets a region whose last readers drained at the PREVIOUS
//    closing barrier (trailing lgkmcnt(0) before every barrier).
//  * a region staged at phase p has all 8 waves' loads vmcnt(8)-drained by
//    each wave at end of phase p+2, workgroup-confirmed by barrier p+2;
//    earliest read is phase p+3.
// Stage cadence (per iteration, tiles T=buf0 / T+1=buf1):
//   ph1(0,0): A[T+1]k1, B[T+1]k1   ph2(0,1): A[T+2]k0, B[T+2]k0
//   ph3(1,0): A[T+2]k1, B[T+2]k1   ph4(1,1): A[T+3]k0, B[T+3]k0
// XCD-aware block remap: linear id % 8 == XCD (round-robin dispatch), so
// n-panel index = (bid&7) + 8*(bid>>7) puts all 16 blocks sharing a w1p
// panel on ONE XCD -> panel streams through that XCD's L2 once instead of
// every XCD fetching it (was ~600 MB L2-miss traffic, 330 MB HBM fetch).
#define WL   "s_waitcnt lgkmcnt(0)"
#define WV8L "s_waitcnt vmcnt(8) lgkmcnt(0)"
#define WV4L "s_waitcnt vmcnt(4) lgkmcnt(0)"
#define WV0L "s_waitcnt vmcnt(0) lgkmcnt(0)"
#define NOSTAGE ((void)0)

#define PH_HALF(p, kh, rh, LOADB, STAGE) do {                                  \
    asm volatile("" ::: "memory");                                             \
    const unsigned short* Ar_ = &lA[((p) * 2 + (kh)) * 8192];                  \
    if (LOADB) {                                                               \
      const unsigned short* Br_ = &lB[((p) * 2 + (kh)) * 8192];                \
      _Pragma("unroll")                                                        \
      for (int j_ = 0; j_ < 4; ++j_)                                           \
        bfc[j_] = *(const bf16x8*)&Br_[(wn * 64 + j_ * 16 + l16) * 32 + fsw];  \
    }                                                                          \
    bf16x8 af_[4];                                                             \
    _Pragma("unroll")                                                          \
    for (int i_ = 0; i_ < 4; ++i_)                                             \
      af_[i_] = *(const bf16x8*)&Ar_[(wm * 128 + (rh) * 64 + i_ * 16 + l16) * 32 + fsw]; \
    STAGE;                                                                     \
    asm volatile("" ::: "memory");                                             \
    __builtin_amdgcn_s_setprio(1);                                             \
    _Pragma("unroll")                                                          \
    for (int i_ = 0; i_ < 4; ++i_)                                             \
      _Pragma("unroll")                                                        \
      for (int j_ = 0; j_ < 4; ++j_)                                           \
        acc[(rh) * 4 + i_][j_] = __builtin_amdgcn_mfma_f32_16x16x32_bf16(      \
            af_[i_], bfc[j_], acc[(rh) * 4 + i_][j_], 0, 0, 0);                \
    __builtin_amdgcn_s_setprio(0);                                             \
  } while (0)

#define PH_END(WAITSTR) do {                                                   \
    asm volatile(WAITSTR ::: "memory");                                        \
    __builtin_amdgcn_s_barrier();                                              \
  } while (0)

__global__ __launch_bounds__(512, 2) void gemm256_conv1(
    const unsigned short* __restrict__ A,   // x1p base (4112 rows x 1024)
    const unsigned short* __restrict__ Bm,  // w1p (4096 x 9216)
    const float* __restrict__ bias,         // b1
    unsigned short* __restrict__ outB) {    // hbuf (4096 x 4096)
  __shared__ alignas(16) unsigned short lA[4 * 8192];  // [buf][kh][256][32]
  __shared__ alignas(16) unsigned short lB[4 * 8192];
  const int tid = threadIdx.x;
  // XCD-aware remap (bijective on 256 blocks): xcd = bid&7 owns n-panels
  // {xcd, xcd+8}; m sweeps 0..15 within the XCD.
  const int bid = blockIdx.x + (blockIdx.y << 4);
  const int nidx = (bid & 7) + ((bid >> 7) << 3);
  const int midx = (bid >> 3) & 15;
  const int m0 = midx * 256, n0 = nidx * 256;
  const int wave = tid >> 6, lane = tid & 63;
  const int wm = wave >> 2, wn = wave & 3;        // 2 x 4 wave grid
  const int l16 = lane & 15, quad = lane >> 4;
  const int fsw = (quad ^ ((l16 >> 1) & 3)) << 3;

  // per-thread staging base offsets (elements), swizzled col
  unsigned int aoff[2], boff[2];
#pragma unroll
  for (int i = 0; i < 2; ++i) {
    const int cf = i * 512 + tid;
    const int row = cf >> 2, cs = cf & 3;
    const int col = (cs ^ ((row >> 1) & 3)) << 3;
    aoff[i] = (unsigned)(m0 + row) * 1024u + (unsigned)col;
    boff[i] = (unsigned)(n0 + row) * 9216u + (unsigned)col;
  }

  floatx4 acc[8][4];
#pragma unroll
  for (int i = 0; i < 8; ++i)
#pragma unroll
    for (int j = 0; j < 4; ++j) acc[i][j] = (floatx4){0.f, 0.f, 0.f, 0.f};
  bf16x8 bfc[4];  // B fragments, reused across the rh pair

  // stage one khalf region (2 x global_load_lds dwordx4 per thread)
  auto stA = [&](int t, int kh) {
    const int p = t & 1;
    const unsigned koff = (unsigned)(t >> 4) * 2048u + (unsigned)((t & 15) * 64 + kh * 32);
#pragma unroll
    for (int i = 0; i < 2; ++i)
      gload_lds16(A + aoff[i] + koff, &lA[(p * 2 + kh) * 8192 + (i * 512 + tid) * 8]);
  };
  auto stB = [&](int t, int kh) {
    const int p = t & 1;
    const unsigned koff = (unsigned)t * 64u + (unsigned)(kh * 32);
#pragma unroll
    for (int i = 0; i < 2; ++i)
      gload_lds16(Bm + boff[i] + koff, &lB[(p * 2 + kh) * 8192 + (i * 512 + tid) * 8]);
  };

  // prologue: tile0 (both khalves) + tile1 kh0 -> 12 loads; drain 4 oldest
  stA(0, 0); stB(0, 0); stA(0, 1); stB(0, 1); stA(1, 0); stB(1, 0);
  asm volatile("s_waitcnt vmcnt(8)" ::: "memory");
  __builtin_amdgcn_s_barrier();

  const int NIT = 72;  // 144 K-tiles / 2 per iteration
  for (int it = 0; it < NIT - 1; ++it) {
    const int T = it * 2;
    PH_HALF(0, 0, 0, 1, stA(T + 1, 1)); PH_HALF(0, 0, 1, 0, stB(T + 1, 1)); PH_END(WV8L);
    PH_HALF(0, 1, 0, 1, stA(T + 2, 0)); PH_HALF(0, 1, 1, 0, stB(T + 2, 0)); PH_END(WV8L);
    PH_HALF(1, 0, 0, 1, stA(T + 2, 1)); PH_HALF(1, 0, 1, 0, stB(T + 2, 1)); PH_END(WV8L);
    PH_HALF(1, 1, 0, 1, stA(T + 3, 0)); PH_HALF(1, 1, 1, 0, stB(T + 3, 0)); PH_END(WV8L);
  }
  {  // last iteration: no prefetch beyond tile NT-1; de-rate waits
    const int T = (NIT - 1) * 2;
    PH_HALF(0, 0, 0, 1, stA(T + 1, 1)); PH_HALF(0, 0, 1, 0, stB(T + 1, 1)); PH_END(WV8L);
    PH_HALF(0, 1, 0, 1, NOSTAGE);       PH_HALF(0, 1, 1, 0, NOSTAGE);       PH_END(WV4L);
    PH_HALF(1, 0, 0, 1, NOSTAGE);       PH_HALF(1, 0, 1, 0, NOSTAGE);       PH_END(WV0L);
    PH_HALF(1, 1, 0, 1, NOSTAGE);       PH_HALF(1, 1, 1, 0, NOSTAGE);       PH_END(WL);
  }

  // epilogue: row = m0 + wm*128 + ii*16 + quad*4 + r, col = n0 + wn*64 + j*16 + l16
#pragma unroll
  for (int ii = 0; ii < 8; ++ii) {
#pragma unroll
    for (int j = 0; j < 4; ++j) {
      const int colg = n0 + wn * 64 + j * 16 + l16;
      const int rbase = m0 + wm * 128 + ii * 16 + quad * 4;
      const float bv = bias[colg];
#pragma unroll
      for (int r = 0; r < 4; ++r)
        outB[(size_t)(rbase + r) * FFC + colg] = f2bf(fmaxf(acc[ii][j][r] + bv, 0.f));
    }
  }
}

// ---------------- flash attention ----------------
__global__ __launch_bounds__(256) void attn_kernel(
    const unsigned short* __restrict__ qg, const unsigned short* __restrict__ kg,
    const unsigned short* __restrict__ vtg, unsigned short* __restrict__ ao) {
  __shared__ alignas(16) unsigned short lK[64 * 64];   // [key][d] swizzled
  __shared__ alignas(16) unsigned short lV[64 * 64];   // [d][key] swizzled
  __shared__ alignas(16) unsigned short lP[4][16 * 64];
  const int tid = threadIdx.x;
  const int wave = tid >> 6, lane = tid & 63;
  const int l16 = lane & 15, quad = lane >> 4;
  const int sw0 = ((quad ^ (l16 & 7)) << 3);
  const int sw1 = (((quad | 4) ^ (l16 & 7)) << 3);
  const int qt = blockIdx.x, h = blockIdx.y, b = blockIdx.z;
  const unsigned short* Q = qg + ((size_t)(b * NHD + h) * LSEQ) * HDD;
  const unsigned short* Kp = kg + ((size_t)(b * NHD + h) * LSEQ) * HDD;
  const unsigned short* Vt = vtg + ((size_t)(b * NHD + h) * HDD) * LSEQ;
  const int q0 = qt * 64 + wave * 16;

  const bf16x8 qa0 = *(const bf16x8*)&Q[(size_t)(q0 + l16) * HDD + quad * 8];
  const bf16x8 qa1 = *(const bf16x8*)&Q[(size_t)(q0 + l16) * HDD + 32 + quad * 8];

  float mr[4], lr[4];
  floatx4 o[4];
#pragma unroll
  for (int r = 0; r < 4; ++r) { mr[r] = -1e30f; lr[r] = 0.f; }
#pragma unroll
  for (int nb = 0; nb < 4; ++nb) o[nb] = (floatx4){0.f, 0.f, 0.f, 0.f};

  for (int kt = 0; kt < LSEQ; kt += 64) {
    __syncthreads();
#pragma unroll
    for (int i = 0; i < 2; ++i) {
      const int flat = i * 256 + tid;
      const int row = flat >> 3, cs = flat & 7;
      const int col = ((cs ^ (row & 7)) << 3);
      gload_lds16(&Kp[(size_t)(kt + row) * HDD + col], &lK[flat * 8]);
      gload_lds16(&Vt[(size_t)row * LSEQ + kt + col], &lV[flat * 8]);
    }
    __syncthreads();
    floatx4 s[4];
#pragma unroll
    for (int nb = 0; nb < 4; ++nb) {
      const bf16x8 kf0 = *(const bf16x8*)&lK[(nb * 16 + l16) * 64 + sw0];
      const bf16x8 kf1 = *(const bf16x8*)&lK[(nb * 16 + l16) * 64 + sw1];
      floatx4 t = (floatx4){0.f, 0.f, 0.f, 0.f};
      t = __builtin_amdgcn_mfma_f32_16x16x32_bf16(qa0, kf0, t, 0, 0, 0);
      t = __builtin_amdgcn_mfma_f32_16x16x32_bf16(qa1, kf1, t, 0, 0, 0);
      s[nb] = t;
    }
    float mnew[4], alpha[4];
#pragma unroll
    for (int r = 0; r < 4; ++r) {
      float mx = fmaxf(fmaxf(s[0][r], s[1][r]), fmaxf(s[2][r], s[3][r]));
      mx = fmaxf(mx, __shfl_xor(mx, 1));
      mx = fmaxf(mx, __shfl_xor(mx, 2));
      mx = fmaxf(mx, __shfl_xor(mx, 4));
      mx = fmaxf(mx, __shfl_xor(mx, 8));
      mnew[r] = fmaxf(mr[r], mx);
      alpha[r] = __expf(mr[r] - mnew[r]);
      mr[r] = mnew[r];
    }
#pragma unroll
    for (int nb = 0; nb < 4; ++nb)
#pragma unroll
      for (int r = 0; r < 4; ++r) s[nb][r] = __expf(s[nb][r] - mnew[r]);
#pragma unroll
    for (int r = 0; r < 4; ++r) {
      float sm = s[0][r] + s[1][r] + s[2][r] + s[3][r];
      sm += __shfl_xor(sm, 1);
      sm += __shfl_xor(sm, 2);
      sm += __shfl_xor(sm, 4);
      sm += __shfl_xor(sm, 8);
      lr[r] = lr[r] * alpha[r] + sm;
    }
#pragma unroll
    for (int nb = 0; nb < 4; ++nb)
#pragma unroll
      for (int r = 0; r < 4; ++r) {
        const int row = quad * 4 + r;
        const int q = nb * 2 + (l16 >> 3);
        lP[wave][row * 64 + ((q ^ (row & 7)) << 3) + (l16 & 7)] = f2bf(s[nb][r]);
        o[nb][r] *= alpha[r];
      }
    asm volatile("s_waitcnt lgkmcnt(0)" ::: "memory");
    const bf16x8 pa0 = *(const bf16x8*)&lP[wave][l16 * 64 + sw0];
    const bf16x8 pa1 = *(const bf16x8*)&lP[wave][l16 * 64 + sw1];
#pragma unroll
    for (int nb = 0; nb < 4; ++nb) {
      const bf16x8 vf0 = *(const bf16x8*)&lV[(nb * 16 + l16) * 64 + sw0];
      const bf16x8 vf1 = *(const bf16x8*)&lV[(nb * 16 + l16) * 64 + sw1];
      o[nb] = __builtin_amdgcn_mfma_f32_16x16x32_bf16(pa0, vf0, o[nb], 0, 0, 0);
      o[nb] = __builtin_amdgcn_mfma_f32_16x16x32_bf16(pa1, vf1, o[nb], 0, 0, 0);
    }
  }
#pragma unroll
  for (int nb = 0; nb < 4; ++nb)
#pragma unroll
    for (int r = 0; r < 4; ++r) {
      const float v = o[nb][r] / lr[r];
      const int lg = q0 + quad * 4 + r;
      ao[((size_t)lg * NB + b) * CCH + h * HDD + nb * 16 + l16] = f2bf(v);
    }
}

// ---------------- layernorm (+residuals) ----------------
__global__ __launch_bounds__(256) void ln_kernel(
    const float* __restrict__ a, const float* __restrict__ c,
    const float* __restrict__ c2, const float* __restrict__ cbias,
    const float* __restrict__ w, const float* __restrict__ bias,
    float* __restrict__ outF, unsigned short* __restrict__ outB) {
  const int row = blockIdx.x;
  const int tid = threadIdx.x;
  const floatx4 va = *(const floatx4*)(a + (size_t)row * 1024 + tid * 4);
  const floatx4 vc = *(const floatx4*)(c + (size_t)row * 1024 + tid * 4);
  float v0 = va[0] + vc[0], v1 = va[1] + vc[1], v2 = va[2] + vc[2], v3 = va[3] + vc[3];
  if (c2) {
    const floatx4 v2c = *(const floatx4*)(c2 + (size_t)row * 1024 + tid * 4);
    v0 += v2c[0]; v1 += v2c[1]; v2 += v2c[2]; v3 += v2c[3];
  }
  if (cbias) {
    const floatx4 vb = *(const floatx4*)(cbias + tid * 4);
    v0 += vb[0]; v1 += vb[1]; v2 += vb[2]; v3 += vb[3];
  }
  float s = v0 + v1 + v2 + v3;
  float ss = v0 * v0 + v1 * v1 + v2 * v2 + v3 * v3;
#pragma unroll
  for (int off = 1; off < 64; off <<= 1) {
    s += __shfl_xor(s, off);
    ss += __shfl_xor(ss, off);
  }
  __shared__ float red[8];
  const int wave = tid >> 6, lane = tid & 63;
  if (lane == 0) { red[wave] = s; red[4 + wave] = ss; }
  __syncthreads();
  s = red[0] + red[1] + red[2] + red[3];
  ss = red[4] + red[5] + red[6] + red[7];
  const float mu = s * (1.f / 1024.f);
  const float var = ss * (1.f / 1024.f) - mu * mu;
  const float rs = rsqrtf(var + 1e-5f);
  const floatx4 wv = *(const floatx4*)(w + tid * 4);
  const floatx4 bv = *(const floatx4*)(bias + tid * 4);
  const float o0 = (v0 - mu) * rs * wv[0] + bv[0];
  const float o1 = (v1 - mu) * rs * wv[1] + bv[1];
  const float o2 = (v2 - mu) * rs * wv[2] + bv[2];
  const float o3 = (v3 - mu) * rs * wv[3] + bv[3];
  *(floatx4*)(outF + (size_t)row * 1024 + tid * 4) = (floatx4){o0, o1, o2, o3};
  if (outB) {
    unsigned long long pk = (unsigned long long)f2bf(o0) |
                            ((unsigned long long)f2bf(o1) << 16) |
                            ((unsigned long long)f2bf(o2) << 32) |
                            ((unsigned long long)f2bf(o3) << 48);
    *(unsigned long long*)(outB + (size_t)row * 1024 + tid * 4) = pk;
  }
}

extern "C" void kernel_launch(void* const* d_in, const int* in_sizes, int n_in,
                              void* d_out, int out_size, void* d_ws, size_t ws_size,
                              hipStream_t stream) {
  const float* x = (const float*)d_in[0];
  const float* wqkv = (const float*)d_in[2];
  const float* bqkv = (const float*)d_in[3];
  const float* wout = (const float*)d_in[4];
  const float* bout = (const float*)d_in[5];
  const float* w1 = (const float*)d_in[6];
  const float* b1 = (const float*)d_in[7];
  const float* w2 = (const float*)d_in[8];
  const float* b2 = (const float*)d_in[9];
  const float* n1w = (const float*)d_in[10];
  const float* n1b = (const float*)d_in[11];
  const float* n2w = (const float*)d_in[12];
  const float* n2b = (const float*)d_in[13];
  float* out = (float*)d_out;

  char* ws = (char*)d_ws;
  size_t off = 0;
  auto alloc = [&](size_t bytes) -> char* {
    char* p = ws + off;
    off += (bytes + 255) & ~(size_t)255;
    return p;
  };
  unsigned short* xb    = (unsigned short*)alloc((size_t)MROWS * 1024 * 2);   // 8.4 MB
  unsigned short* wqkvb = (unsigned short*)alloc((size_t)3072 * 1024 * 2);    // 6.3 MB
  unsigned short* woutb = (unsigned short*)alloc((size_t)1024 * 1024 * 2);    // 2.1 MB
  unsigned short* w1p   = (unsigned short*)alloc((size_t)FFC * 9216 * 2);
  unsigned short* w2b   = (unsigned short*)alloc((size_t)1024 * FFC * 2);
  unsigned short* qbuf  = (unsigned short*)alloc((size_t)NB * NHD * LSEQ * HDD * 2);
  unsigned short* kbuf  = (unsigned short*)alloc((size_t)NB * NHD * LSEQ * HDD * 2);
  unsigned short* vtbuf = (unsigned short*)alloc((size_t)NB * NHD * LSEQ * HDD * 2);
  unsigned short* ao    = (unsigned short*)alloc((size_t)MROWS * 1024 * 2);
  float*          yz    = (float*)alloc((size_t)MROWS * 1024 * 4);
  float*          x1f   = (float*)alloc((size_t)MROWS * 1024 * 4);
  unsigned short* x1p   = (unsigned short*)alloc((size_t)(LSEQ + 8) * NB * 1024 * 2);
  unsigned short* hbuf  = (unsigned short*)alloc((size_t)MROWS * FFC * 2);
  if (off > ws_size) return;  // workspace too small -> visible failure
  // dead-region aliases (no extra ws):
  float*          yzB   = (float*)xb;
  unsigned short* vbuf  = hbuf;

  int n;
  n = MROWS * 1024 / 4; f2bf4_kernel<<<(n + 255) / 256, 256, 0, stream>>>(x, xb, n);
  n = 3072 * 1024 / 4;  f2bf4_kernel<<<(n + 255) / 256, 256, 0, stream>>>(wqkv, wqkvb, n);
  n = 1024 * 1024 / 4;  f2bf4_kernel<<<(n + 255) / 256, 256, 0, stream>>>(wout, woutb, n);
  n = 1024 * FFC / 4;   f2bf4_kernel<<<(n + 255) / 256, 256, 0, stream>>>(w2, w2b, n);
  repack_w1_kernel<<<FFC, 256, 0, stream>>>(w1, w1p);
  zero_u16<<<32, 256, 0, stream>>>(x1p, 8 * 1024);
  zero_u16<<<32, 256, 0, stream>>>(x1p + (size_t)(LSEQ + 4) * NB * 1024, 8 * 1024);

  // QKV projection (M=4096, N=3072, K=1024); q/k/v all natural [b,h,l,d]
  gemm_bt<0, false, 128><<<dim3(32, 24), 256, 0, stream>>>(
      xb, wqkvb, bqkv, 3072, 1024, 1024, nullptr, nullptr, nullptr, qbuf, kbuf, vbuf);
  // V -> V^T (coalesced LDS transpose)
  transpose_v_kernel<<<dim3(LSEQ / 64, NB * NHD), 256, 0, stream>>>(vbuf, vtbuf);
  // flash attention -> ao (L*B, C) bf16
  attn_kernel<<<dim3(LSEQ / 64, NHD, NB), 256, 0, stream>>>(qbuf, kbuf, vtbuf, ao);
  // out projection (M=4096, N=1024, K=1024) -> yz fp32
  gemm_bt<1, false, 64><<<dim3(32, 16), 256, 0, stream>>>(
      ao, woutb, bout, 1024, 1024, 1024, yz, nullptr, nullptr, nullptr, nullptr, nullptr);
  // LN1: x + yz -> x1f fp32, x1p bf16 (shifted +8 rows for l-padding)
  ln_kernel<<<MROWS, 256, 0, stream>>>(x, yz, nullptr, nullptr, n1w, n1b, x1f, x1p + 8 * 1024);
  // conv1 as 256x256 4-phase GEMM (M=4096, N=4096, K=9216) + bias + relu -> hbuf bf16
  gemm256_conv1<<<dim3(16, 16), 512, 0, stream>>>(x1p, w1p, b1, hbuf);
  // conv2 pointwise (M=4096, N=1024, K=4096) split-K x2 -> yz, yzB (raw, bias in LN2)
  gemm_bt<1, false, 64><<<dim3(32, 16, 2), 256, 0, stream>>>(
      hbuf, w2b, nullptr, 1024, FFC, 2048, yz, yzB, nullptr, nullptr, nullptr, nullptr);
  // LN2: x1f + yz + yzB + b2 -> out fp32
  ln_kernel<<<MROWS, 256, 0, stream>>>(x1f, yz, yzB, b2, n2w, n2b, out, nullptr);
}

// Round 5
// 833.691 us; speedup vs baseline: 1.0270x; 1.0056x over previous
//
#include <hip/hip_runtime.h>
#include <cstdint>
#include <cstddef>

// Problem constants
#define LSEQ 2048
#define NB   2      // batch
#define CCH  1024   // channels
#define NHD  16     // heads
#define HDD  64     // head dim
#define FFC  4096   // conv hidden
#define KW   9      // conv kernel width
#define MROWS 4096  // L*B

typedef __bf16 bf16x8 __attribute__((ext_vector_type(8)));
typedef float  floatx4 __attribute__((ext_vector_type(4)));
typedef unsigned short ushort4v __attribute__((ext_vector_type(4)));

__device__ inline unsigned short f2bf(float f) {
  union { float f; unsigned u; } v; v.f = f;
  unsigned r = v.u + 0x7FFFu + ((v.u >> 16) & 1u);
  return (unsigned short)(r >> 16);
}

// async global->LDS, 16B per lane. Dest must be wave-uniform base + lane*16.
__device__ inline void gload_lds16(const unsigned short* g, unsigned short* l) {
  __builtin_amdgcn_global_load_lds(
      (__attribute__((address_space(1))) unsigned int*)(g),
      (__attribute__((address_space(3))) unsigned int*)(l), 16, 0, 0);
}

// ---------------- element-wise converts ----------------
__global__ void f2bf4_kernel(const float* __restrict__ in, unsigned short* __restrict__ out, int n4) {
  int idx = blockIdx.x * 256 + threadIdx.x;
  if (idx >= n4) return;
  const floatx4 v = ((const floatx4*)in)[idx];
  unsigned long long pk = (unsigned long long)f2bf(v[0]) |
                          ((unsigned long long)f2bf(v[1]) << 16) |
                          ((unsigned long long)f2bf(v[2]) << 32) |
                          ((unsigned long long)f2bf(v[3]) << 48);
  ((unsigned long long*)out)[idx] = pk;
}

// conv1_w (FF, C, K) fp32 -> w1p[f*9216 + k*1024 + c] bf16.
__global__ __launch_bounds__(256) void repack_w1_kernel(const float* __restrict__ in,
                                                        unsigned short* __restrict__ out) {
  __shared__ unsigned short t[9216];
  const int f = blockIdx.x, tid = threadIdx.x;
  const float* src = in + (size_t)f * 9216;
#pragma unroll
  for (int rnd = 0; rnd < 9; ++rnd) {
    const int p = (rnd * 256 + tid) * 4;
    const floatx4 v = *(const floatx4*)(src + p);
#pragma unroll
    for (int e = 0; e < 4; ++e) {
      const int idx = p + e;
      const int c = idx / 9, k = idx - c * 9;
      t[k * 1024 + c] = f2bf(v[e]);
    }
  }
  __syncthreads();
  unsigned short* dst = out + (size_t)f * 9216;
#pragma unroll
  for (int rnd = 0; rnd < 9; ++rnd) {
    const int j = (rnd * 256 + tid) * 4;
    *(ushort4v*)(dst + j) = *(const ushort4v*)&t[j];
  }
}

__global__ void zero_u16(unsigned short* p, int n) {
  int idx = blockIdx.x * 256 + threadIdx.x;
  if (idx < n) p[idx] = 0;
}

// V [bh][l][d] -> V^T [bh][d][l].  64x64 tile per block, LDS transpose,
// coalesced 8B on both sides.
__global__ __launch_bounds__(256) void transpose_v_kernel(
    const unsigned short* __restrict__ vin, unsigned short* __restrict__ vout) {
  __shared__ unsigned short t[64][65];
  const int tid = threadIdx.x;
  const int l0 = blockIdx.x * 64, bh = blockIdx.y;
  const unsigned short* src = vin + ((size_t)bh * LSEQ + l0) * HDD;
  const int rr = tid >> 4, cc = (tid & 15) * 4;
#pragma unroll
  for (int rnd = 0; rnd < 4; ++rnd) {
    const int row = rnd * 16 + rr;
    const ushort4v v = *(const ushort4v*)(src + row * HDD + cc);
#pragma unroll
    for (int e = 0; e < 4; ++e) t[row][cc + e] = v[e];
  }
  __syncthreads();
  unsigned short* dst = vout + (size_t)bh * HDD * LSEQ + l0;
#pragma unroll
  for (int rnd = 0; rnd < 4; ++rnd) {
    const int drow = rnd * 16 + rr;
    ushort4v v;
#pragma unroll
    for (int e = 0; e < 4; ++e) v[e] = t[cc + e][drow];
    *(ushort4v*)(dst + (size_t)drow * LSEQ + cc) = v;
  }
}

// ---------------- GEMM: C = A(MxK) * B(NxK)^T + bias ----------------
// 128xBN tile, BK=32, 4 waves, 16x16x32 bf16 MFMA, global_load_lds width=16,
// XOR swizzle (0 conflicts).  Used for QKV / out-proj / conv2.
template <int EPI, bool KDEC, int BN>
__global__ __launch_bounds__(256) void gemm_bt(
    const unsigned short* __restrict__ A, const unsigned short* __restrict__ Bm,
    const float* __restrict__ bias, int N, int Kstride, int Klen,
    float* __restrict__ outF, float* __restrict__ outF2,
    unsigned short* __restrict__ outB,
    unsigned short* __restrict__ qb, unsigned short* __restrict__ kb,
    unsigned short* __restrict__ vb) {
  constexpr int JN = BN / 32;  // j-fragments per wave
  __shared__ alignas(16) unsigned short lA[128 * 32];
  __shared__ alignas(16) unsigned short lB[BN * 32];
  const int tid = threadIdx.x;
  const int m0 = blockIdx.x * 128;
  const int n0 = blockIdx.y * BN;
  const int z = blockIdx.z;
  A += (size_t)z * Klen;
  Bm += (size_t)z * Klen;
  const int wave = tid >> 6, lane = tid & 63;
  const int wm = (wave >> 1) * 64, wn = (wave & 1) * (BN / 2);
  const int l16 = lane & 15, quad = lane >> 4;
  const int fsw = (quad ^ ((l16 >> 1) & 3)) << 3;

  size_t aoff[2], boff[BN / 64];
#pragma unroll
  for (int i = 0; i < 2; ++i) {
    const int cf = i * 256 + tid;
    const int row = cf >> 2, cs = cf & 3;
    const int col = ((cs ^ ((row >> 1) & 3)) << 3);
    aoff[i] = (KDEC ? (size_t)row * 1024 : (size_t)(m0 + row) * Kstride) + col;
  }
#pragma unroll
  for (int i = 0; i < BN / 64; ++i) {
    const int cf = i * 256 + tid;
    const int row = cf >> 2, cs = cf & 3;
    const int col = ((cs ^ ((row >> 1) & 3)) << 3);
    boff[i] = (size_t)(n0 + row) * Kstride + col;
  }

  floatx4 acc[4][JN];
#pragma unroll
  for (int i = 0; i < 4; ++i)
#pragma unroll
    for (int j = 0; j < JN; ++j) acc[i][j] = (floatx4){0.f, 0.f, 0.f, 0.f};

  auto kstep = [&](const unsigned short* Ab, const unsigned short* Bb) {
    __syncthreads();
#pragma unroll
    for (int i = 0; i < 2; ++i)
      gload_lds16(Ab + aoff[i], &lA[(i * 256 + tid) * 8]);
#pragma unroll
    for (int i = 0; i < BN / 64; ++i)
      gload_lds16(Bb + boff[i], &lB[(i * 256 + tid) * 8]);
    __syncthreads();
    bf16x8 af[4], bf[JN];
#pragma unroll
    for (int i = 0; i < 4; ++i)
      af[i] = *(const bf16x8*)&lA[(wm + i * 16 + l16) * 32 + fsw];
#pragma unroll
    for (int j = 0; j < JN; ++j)
      bf[j] = *(const bf16x8*)&lB[(wn + j * 16 + l16) * 32 + fsw];
#pragma unroll
    for (int i = 0; i < 4; ++i)
#pragma unroll
      for (int j = 0; j < JN; ++j)
        acc[i][j] = __builtin_amdgcn_mfma_f32_16x16x32_bf16(af[i], bf[j], acc[i][j], 0, 0, 0);
  };

  if (KDEC) {
    for (int seg = 0; seg < KW; ++seg) {
      const unsigned short* Ab = A + (size_t)(m0 + seg * NB) * 1024;
      const unsigned short* Bb = Bm + seg * 1024;
      for (int kk = 0; kk < 1024; kk += 32) kstep(Ab + kk, Bb + kk);
    }
  } else {
    for (int k0 = 0; k0 < Klen; k0 += 32) kstep(A + k0, Bm + k0);
  }

  float* outZ = (z == 0) ? outF : outF2;
#pragma unroll
  for (int i = 0; i < 4; ++i) {
#pragma unroll
    for (int j = 0; j < JN; ++j) {
      const int colg = n0 + wn + j * 16 + l16;
      const int rbase = m0 + wm + i * 16 + quad * 4;
      const float bv = bias ? bias[colg] : 0.f;
      float vv[4];
#pragma unroll
      for (int r = 0; r < 4; ++r) vv[r] = acc[i][j][r] + bv;
      if (EPI == 1) {
#pragma unroll
        for (int r = 0; r < 4; ++r) outZ[(size_t)(rbase + r) * N + colg] = vv[r];
      } else if (EPI == 2) {
#pragma unroll
        for (int r = 0; r < 4; ++r)
          outB[(size_t)(rbase + r) * N + colg] = f2bf(fmaxf(vv[r], 0.f));
      } else {
        const int seg = colg >> 10;  // 0:q 1:k 2:v
        const int c = colg & 1023, h = c >> 6, d = c & 63;
        unsigned short* dst = (seg == 0) ? qb : (seg == 1) ? kb : vb;
        const float scl = (seg == 0) ? 0.125f : 1.f;
#pragma unroll
        for (int r = 0; r < 4; ++r) {
          const int row = rbase + r, l = row >> 1, b = row & 1;
          dst[(((size_t)(b * NHD + h)) * LSEQ + l) * HDD + d] = f2bf(vv[r] * scl);
        }
      }
    }
  }
}

// ---------------- conv1 as 256x256 4-phase GEMM, fused-phase form --------
// out[m][f] = relu( sum_{seg,c} x1p[(m+seg*2)*1024+c] * w1p[f*9216+seg*1024+c] + b1[f] )
// M=N=4096, K=9216 (144 K-tiles of BK=64).  8 waves (2Mx4N), 512 thr.
// LDS 128 KiB: per matrix 2 buf x 2 khalf regions of [256 rows][32 K] bf16.
//
// Phase (one khalf) = SINGLE fenced region:
//   issue ALL 12 ds_read_b128 (bfc[4], af0[4], af1[4]) + both stage units,
//   then the full 32-MFMA cluster, then s_waitcnt vmcnt(8) lgkmcnt(0) +
//   s_barrier.  R4 had a compiler memory-fence mid-phase, which forbade
//   hoisting rh1's reads past rh0's MFMAs -> CU-level read-burst THEN
//   MFMA-burst (sum, not overlap; phase 2560cy = 1240 MFMA + ~1300 LDS).
//   With one region the compiler's fine-grained lgkmcnt lets MFMAs start
//   after 8 reads while the read tail + other waves' reads overlap the
//   MFMA section.  Barrier count/placement and stage/wait cadence are
//   IDENTICAL to the R4-verified pipeline, so the region-hazard proof
//   carries over unchanged:
//  * stage targets a region whose last readers drained at the PREVIOUS
//    closing barrier (trailing lgkmcnt(0) before every barrier).
//  * a region staged at phase p is vmcnt(8)-drained by end of p+2 and
//    workgroup-confirmed by barrier p+2; earliest read is phase p+3.
// Stage cadence (per iteration, tiles T=buf0 / T+1=buf1):
//   ph1(0,0): A[T+1]k1, B[T+1]k1   ph2(0,1): A[T+2]k0, B[T+2]k0
//   ph3(1,0): A[T+2]k1, B[T+2]k1   ph4(1,1): A[T+3]k0, B[T+3]k0
// NOTE: no XCD remap — R4 measured it as a regression (FETCH 330->373 MB;
// a 4.7 MB w1p panel exceeds the 4 MB per-XCD L2, pinning 2 panels/XCD
// thrashes).  Default round-robin keeps 2 blocks/panel/XCD temporally
// adjacent, which caches better.
#define WL   "s_waitcnt lgkmcnt(0)"
#define WV8L "s_waitcnt vmcnt(8) lgkmcnt(0)"
#define WV4L "s_waitcnt vmcnt(4) lgkmcnt(0)"
#define WV0L "s_waitcnt vmcnt(0) lgkmcnt(0)"
#define NOSTAGE ((void)0)

#define PHASE(p, kh, STA, STB, WAITSTR) do {                                   \
    asm volatile("" ::: "memory");                                             \
    const unsigned short* Ar_ = &lA[((p) * 2 + (kh)) * 8192];                  \
    const unsigned short* Br_ = &lB[((p) * 2 + (kh)) * 8192];                  \
    bf16x8 bfc_[4], af0_[4], af1_[4];                                          \
    _Pragma("unroll")                                                          \
    for (int j_ = 0; j_ < 4; ++j_)                                             \
      bfc_[j_] = *(const bf16x8*)&Br_[(wn * 64 + j_ * 16 + l16) * 32 + fsw];   \
    _Pragma("unroll")                                                          \
    for (int i_ = 0; i_ < 4; ++i_)                                             \
      af0_[i_] = *(const bf16x8*)&Ar_[(wm * 128 + i_ * 16 + l16) * 32 + fsw];  \
    _Pragma("unroll")                                                          \
    for (int i_ = 0; i_ < 4; ++i_)                                             \
      af1_[i_] = *(const bf16x8*)&Ar_[(wm * 128 + 64 + i_ * 16 + l16) * 32 + fsw]; \
    STA;                                                                       \
    STB;                                                                       \
    __builtin_amdgcn_s_setprio(1);                                             \
    _Pragma("unroll")                                                          \
    for (int i_ = 0; i_ < 4; ++i_)                                             \
      _Pragma("unroll")                                                        \
      for (int j_ = 0; j_ < 4; ++j_)                                           \
        acc[i_][j_] = __builtin_amdgcn_mfma_f32_16x16x32_bf16(                 \
            af0_[i_], bfc_[j_], acc[i_][j_], 0, 0, 0);                         \
    _Pragma("unroll")                                                          \
    for (int i_ = 0; i_ < 4; ++i_)                                             \
      _Pragma("unroll")                                                        \
      for (int j_ = 0; j_ < 4; ++j_)                                           \
        acc[4 + i_][j_] = __builtin_amdgcn_mfma_f32_16x16x32_bf16(             \
            af1_[i_], bfc_[j_], acc[4 + i_][j_], 0, 0, 0);                     \
    __builtin_amdgcn_s_setprio(0);                                             \
    asm volatile(WAITSTR ::: "memory");                                        \
    __builtin_amdgcn_s_barrier();                                              \
  } while (0)

__global__ __launch_bounds__(512, 2) void gemm256_conv1(
    const unsigned short* __restrict__ A,   // x1p base (4112 rows x 1024)
    const unsigned short* __restrict__ Bm,  // w1p (4096 x 9216)
    const float* __restrict__ bias,         // b1
    unsigned short* __restrict__ outB) {    // hbuf (4096 x 4096)
  __shared__ alignas(16) unsigned short lA[4 * 8192];  // [buf][kh][256][32]
  __shared__ alignas(16) unsigned short lB[4 * 8192];
  const int tid = threadIdx.x;
  const int m0 = blockIdx.x * 256, n0 = blockIdx.y * 256;
  const int wave = tid >> 6, lane = tid & 63;
  const int wm = wave >> 2, wn = wave & 3;        // 2 x 4 wave grid
  const int l16 = lane & 15, quad = lane >> 4;
  const int fsw = (quad ^ ((l16 >> 1) & 3)) << 3;

  // per-thread staging base offsets (elements), swizzled col
  unsigned int aoff[2], boff[2];
#pragma unroll
  for (int i = 0; i < 2; ++i) {
    const int cf = i * 512 + tid;
    const int row = cf >> 2, cs = cf & 3;
    const int col = (cs ^ ((row >> 1) & 3)) << 3;
    aoff[i] = (unsigned)(m0 + row) * 1024u + (unsigned)col;
    boff[i] = (unsigned)(n0 + row) * 9216u + (unsigned)col;
  }

  floatx4 acc[8][4];
#pragma unroll
  for (int i = 0; i < 8; ++i)
#pragma unroll
    for (int j = 0; j < 4; ++j) acc[i][j] = (floatx4){0.f, 0.f, 0.f, 0.f};

  // stage one khalf region (2 x global_load_lds dwordx4 per thread)
  auto stA = [&](int t, int kh) {
    const int p = t & 1;
    const unsigned koff = (unsigned)(t >> 4) * 2048u + (unsigned)((t & 15) * 64 + kh * 32);
#pragma unroll
    for (int i = 0; i < 2; ++i)
      gload_lds16(A + aoff[i] + koff, &lA[(p * 2 + kh) * 8192 + (i * 512 + tid) * 8]);
  };
  auto stB = [&](int t, int kh) {
    const int p = t & 1;
    const unsigned koff = (unsigned)t * 64u + (unsigned)(kh * 32);
#pragma unroll
    for (int i = 0; i < 2; ++i)
      gload_lds16(Bm + boff[i] + koff, &lB[(p * 2 + kh) * 8192 + (i * 512 + tid) * 8]);
  };

  // prologue: tile0 (both khalves) + tile1 kh0 -> 12 loads; drain 4 oldest
  stA(0, 0); stB(0, 0); stA(0, 1); stB(0, 1); stA(1, 0); stB(1, 0);
  asm volatile("s_waitcnt vmcnt(8)" ::: "memory");
  __builtin_amdgcn_s_barrier();

  const int NIT = 72;  // 144 K-tiles / 2 per iteration
  for (int it = 0; it < NIT - 1; ++it) {
    const int T = it * 2;
    PHASE(0, 0, stA(T + 1, 1), stB(T + 1, 1), WV8L);
    PHASE(0, 1, stA(T + 2, 0), stB(T + 2, 0), WV8L);
    PHASE(1, 0, stA(T + 2, 1), stB(T + 2, 1), WV8L);
    PHASE(1, 1, stA(T + 3, 0), stB(T + 3, 0), WV8L);
  }
  {  // last iteration: no prefetch beyond tile NT-1; de-rate waits
    PHASE(0, 0, stA(143, 1), stB(143, 1), WV8L);
    PHASE(0, 1, NOSTAGE, NOSTAGE, WV4L);
    PHASE(1, 0, NOSTAGE, NOSTAGE, WV0L);
    PHASE(1, 1, NOSTAGE, NOSTAGE, WL);
  }

  // epilogue: row = m0 + wm*128 + ii*16 + quad*4 + r, col = n0 + wn*64 + j*16 + l16
#pragma unroll
  for (int ii = 0; ii < 8; ++ii) {
#pragma unroll
    for (int j = 0; j < 4; ++j) {
      const int colg = n0 + wn * 64 + j * 16 + l16;
      const int rbase = m0 + wm * 128 + ii * 16 + quad * 4;
      const float bv = bias[colg];
#pragma unroll
      for (int r = 0; r < 4; ++r)
        outB[(size_t)(rbase + r) * FFC + colg] = f2bf(fmaxf(acc[ii][j][r] + bv, 0.f));
    }
  }
}

// ---------------- flash attention ----------------
__global__ __launch_bounds__(256) void attn_kernel(
    const unsigned short* __restrict__ qg, const unsigned short* __restrict__ kg,
    const unsigned short* __restrict__ vtg, unsigned short* __restrict__ ao) {
  __shared__ alignas(16) unsigned short lK[64 * 64];   // [key][d] swizzled
  __shared__ alignas(16) unsigned short lV[64 * 64];   // [d][key] swizzled
  __shared__ alignas(16) unsigned short lP[4][16 * 64];
  const int tid = threadIdx.x;
  const int wave = tid >> 6, lane = tid & 63;
  const int l16 = lane & 15, quad = lane >> 4;
  const int sw0 = ((quad ^ (l16 & 7)) << 3);
  const int sw1 = (((quad | 4) ^ (l16 & 7)) << 3);
  const int qt = blockIdx.x, h = blockIdx.y, b = blockIdx.z;
  const unsigned short* Q = qg + ((size_t)(b * NHD + h) * LSEQ) * HDD;
  const unsigned short* Kp = kg + ((size_t)(b * NHD + h) * LSEQ) * HDD;
  const unsigned short* Vt = vtg + ((size_t)(b * NHD + h) * HDD) * LSEQ;
  const int q0 = qt * 64 + wave * 16;

  const bf16x8 qa0 = *(const bf16x8*)&Q[(size_t)(q0 + l16) * HDD + quad * 8];
  const bf16x8 qa1 = *(const bf16x8*)&Q[(size_t)(q0 + l16) * HDD + 32 + quad * 8];

  float mr[4], lr[4];
  floatx4 o[4];
#pragma unroll
  for (int r = 0; r < 4; ++r) { mr[r] = -1e30f; lr[r] = 0.f; }
#pragma unroll
  for (int nb = 0; nb < 4; ++nb) o[nb] = (floatx4){0.f, 0.f, 0.f, 0.f};

  for (int kt = 0; kt < LSEQ; kt += 64) {
    __syncthreads();
#pragma unroll
    for (int i = 0; i < 2; ++i) {
      const int flat = i * 256 + tid;
      const int row = flat >> 3, cs = flat & 7;
      const int col = ((cs ^ (row & 7)) << 3);
      gload_lds16(&Kp[(size_t)(kt + row) * HDD + col], &lK[flat * 8]);
      gload_lds16(&Vt[(size_t)row * LSEQ + kt + col], &lV[flat * 8]);
    }
    __syncthreads();
    floatx4 s[4];
#pragma unroll
    for (int nb = 0; nb < 4; ++nb) {
      const bf16x8 kf0 = *(const bf16x8*)&lK[(nb * 16 + l16) * 64 + sw0];
      const bf16x8 kf1 = *(const bf16x8*)&lK[(nb * 16 + l16) * 64 + sw1];
      floatx4 t = (floatx4){0.f, 0.f, 0.f, 0.f};
      t = __builtin_amdgcn_mfma_f32_16x16x32_bf16(qa0, kf0, t, 0, 0, 0);
      t = __builtin_amdgcn_mfma_f32_16x16x32_bf16(qa1, kf1, t, 0, 0, 0);
      s[nb] = t;
    }
    float mnew[4], alpha[4];
#pragma unroll
    for (int r = 0; r < 4; ++r) {
      float mx = fmaxf(fmaxf(s[0][r], s[1][r]), fmaxf(s[2][r], s[3][r]));
      mx = fmaxf(mx, __shfl_xor(mx, 1));
      mx = fmaxf(mx, __shfl_xor(mx, 2));
      mx = fmaxf(mx, __shfl_xor(mx, 4));
      mx = fmaxf(mx, __shfl_xor(mx, 8));
      mnew[r] = fmaxf(mr[r], mx);
      alpha[r] = __expf(mr[r] - mnew[r]);
      mr[r] = mnew[r];
    }
#pragma unroll
    for (int nb = 0; nb < 4; ++nb)
#pragma unroll
      for (int r = 0; r < 4; ++r) s[nb][r] = __expf(s[nb][r] - mnew[r]);
#pragma unroll
    for (int r = 0; r < 4; ++r) {
      float sm = s[0][r] + s[1][r] + s[2][r] + s[3][r];
      sm += __shfl_xor(sm, 1);
      sm += __shfl_xor(sm, 2);
      sm += __shfl_xor(sm, 4);
      sm += __shfl_xor(sm, 8);
      lr[r] = lr[r] * alpha[r] + sm;
    }
#pragma unroll
    for (int nb = 0; nb < 4; ++nb)
#pragma unroll
      for (int r = 0; r < 4; ++r) {
        const int row = quad * 4 + r;
        const int q = nb * 2 + (l16 >> 3);
        lP[wave][row * 64 + ((q ^ (row & 7)) << 3) + (l16 & 7)] = f2bf(s[nb][r]);
        o[nb][r] *= alpha[r];
      }
    asm volatile("s_waitcnt lgkmcnt(0)" ::: "memory");
    const bf16x8 pa0 = *(const bf16x8*)&lP[wave][l16 * 64 + sw0];
    const bf16x8 pa1 = *(const bf16x8*)&lP[wave][l16 * 64 + sw1];
#pragma unroll
    for (int nb = 0; nb < 4; ++nb) {
      const bf16x8 vf0 = *(const bf16x8*)&lV[(nb * 16 + l16) * 64 + sw0];
      const bf16x8 vf1 = *(const bf16x8*)&lV[(nb * 16 + l16) * 64 + sw1];
      o[nb] = __builtin_amdgcn_mfma_f32_16x16x32_bf16(pa0, vf0, o[nb], 0, 0, 0);
      o[nb] = __builtin_amdgcn_mfma_f32_16x16x32_bf16(pa1, vf1, o[nb], 0, 0, 0);
    }
  }
#pragma unroll
  for (int nb = 0; nb < 4; ++nb)
#pragma unroll
    for (int r = 0; r < 4; ++r) {
      const float v = o[nb][r] / lr[r];
      const int lg = q0 + quad * 4 + r;
      ao[((size_t)lg * NB + b) * CCH + h * HDD + nb * 16 + l16] = f2bf(v);
    }
}

// ---------------- layernorm (+residuals) ----------------
__global__ __launch_bounds__(256) void ln_kernel(
    const float* __restrict__ a, const float* __restrict__ c,
    const float* __restrict__ c2, const float* __restrict__ cbias,
    const float* __restrict__ w, const float* __restrict__ bias,
    float* __restrict__ outF, unsigned short* __restrict__ outB) {
  const int row = blockIdx.x;
  const int tid = threadIdx.x;
  const floatx4 va = *(const floatx4*)(a + (size_t)row * 1024 + tid * 4);
  const floatx4 vc = *(const floatx4*)(c + (size_t)row * 1024 + tid * 4);
  float v0 = va[0] + vc[0], v1 = va[1] + vc[1], v2 = va[2] + vc[2], v3 = va[3] + vc[3];
  if (c2) {
    const floatx4 v2c = *(const floatx4*)(c2 + (size_t)row * 1024 + tid * 4);
    v0 += v2c[0]; v1 += v2c[1]; v2 += v2c[2]; v3 += v2c[3];
  }
  if (cbias) {
    const floatx4 vb = *(const floatx4*)(cbias + tid * 4);
    v0 += vb[0]; v1 += vb[1]; v2 += vb[2]; v3 += vb[3];
  }
  float s = v0 + v1 + v2 + v3;
  float ss = v0 * v0 + v1 * v1 + v2 * v2 + v3 * v3;
#pragma unroll
  for (int off = 1; off < 64; off <<= 1) {
    s += __shfl_xor(s, off);
    ss += __shfl_xor(ss, off);
  }
  __shared__ float red[8];
  const int wave = tid >> 6, lane = tid & 63;
  if (lane == 0) { red[wave] = s; red[4 + wave] = ss; }
  __syncthreads();
  s = red[0] + red[1] + red[2] + red[3];
  ss = red[4] + red[5] + red[6] + red[7];
  const float mu = s * (1.f / 1024.f);
  const float var = ss * (1.f / 1024.f) - mu * mu;
  const float rs = rsqrtf(var + 1e-5f);
  const floatx4 wv = *(const floatx4*)(w + tid * 4);
  const floatx4 bv = *(const floatx4*)(bias + tid * 4);
  const float o0 = (v0 - mu) * rs * wv[0] + bv[0];
  const float o1 = (v1 - mu) * rs * wv[1] + bv[1];
  const float o2 = (v2 - mu) * rs * wv[2] + bv[2];
  const float o3 = (v3 - mu) * rs * wv[3] + bv[3];
  *(floatx4*)(outF + (size_t)row * 1024 + tid * 4) = (floatx4){o0, o1, o2, o3};
  if (outB) {
    unsigned long long pk = (unsigned long long)f2bf(o0) |
                            ((unsigned long long)f2bf(o1) << 16) |
                            ((unsigned long long)f2bf(o2) << 32) |
                            ((unsigned long long)f2bf(o3) << 48);
    *(unsigned long long*)(outB + (size_t)row * 1024 + tid * 4) = pk;
  }
}

extern "C" void kernel_launch(void* const* d_in, const int* in_sizes, int n_in,
                              void* d_out, int out_size, void* d_ws, size_t ws_size,
                              hipStream_t stream) {
  const float* x = (const float*)d_in[0];
  const float* wqkv = (const float*)d_in[2];
  const float* bqkv = (const float*)d_in[3];
  const float* wout = (const float*)d_in[4];
  const float* bout = (const float*)d_in[5];
  const float* w1 = (const float*)d_in[6];
  const float* b1 = (const float*)d_in[7];
  const float* w2 = (const float*)d_in[8];
  const float* b2 = (const float*)d_in[9];
  const float* n1w = (const float*)d_in[10];
  const float* n1b = (const float*)d_in[11];
  const float* n2w = (const float*)d_in[12];
  const float* n2b = (const float*)d_in[13];
  float* out = (float*)d_out;

  char* ws = (char*)d_ws;
  size_t off = 0;
  auto alloc = [&](size_t bytes) -> char* {
    char* p = ws + off;
    off += (bytes + 255) & ~(size_t)255;
    return p;
  };
  unsigned short* xb    = (unsigned short*)alloc((size_t)MROWS * 1024 * 2);   // 8.4 MB
  unsigned short* wqkvb = (unsigned short*)alloc((size_t)3072 * 1024 * 2);    // 6.3 MB
  unsigned short* woutb = (unsigned short*)alloc((size_t)1024 * 1024 * 2);    // 2.1 MB
  unsigned short* w1p   = (unsigned short*)alloc((size_t)FFC * 9216 * 2);
  unsigned short* w2b   = (unsigned short*)alloc((size_t)1024 * FFC * 2);
  unsigned short* qbuf  = (unsigned short*)alloc((size_t)NB * NHD * LSEQ * HDD * 2);
  unsigned short* kbuf  = (unsigned short*)alloc((size_t)NB * NHD * LSEQ * HDD * 2);
  unsigned short* vtbuf = (unsigned short*)alloc((size_t)NB * NHD * LSEQ * HDD * 2);
  unsigned short* ao    = (unsigned short*)alloc((size_t)MROWS * 1024 * 2);
  float*          yz    = (float*)alloc((size_t)MROWS * 1024 * 4);
  float*          x1f   = (float*)alloc((size_t)MROWS * 1024 * 4);
  unsigned short* x1p   = (unsigned short*)alloc((size_t)(LSEQ + 8) * NB * 1024 * 2);
  unsigned short* hbuf  = (unsigned short*)alloc((size_t)MROWS * FFC * 2);
  if (off > ws_size) return;  // workspace too small -> visible failure
  // dead-region aliases (no extra ws):
  float*          yzB   = (float*)xb;
  unsigned short* vbuf  = hbuf;

  int n;
  n = MROWS * 1024 / 4; f2bf4_kernel<<<(n + 255) / 256, 256, 0, stream>>>(x, xb, n);
  n = 3072 * 1024 / 4;  f2bf4_kernel<<<(n + 255) / 256, 256, 0, stream>>>(wqkv, wqkvb, n);
  n = 1024 * 1024 / 4;  f2bf4_kernel<<<(n + 255) / 256, 256, 0, stream>>>(wout, woutb, n);
  n = 1024 * FFC / 4;   f2bf4_kernel<<<(n + 255) / 256, 256, 0, stream>>>(w2, w2b, n);
  repack_w1_kernel<<<FFC, 256, 0, stream>>>(w1, w1p);
  zero_u16<<<32, 256, 0, stream>>>(x1p, 8 * 1024);
  zero_u16<<<32, 256, 0, stream>>>(x1p + (size_t)(LSEQ + 4) * NB * 1024, 8 * 1024);

  // QKV projection (M=4096, N=3072, K=1024); q/k/v all natural [b,h,l,d]
  gemm_bt<0, false, 128><<<dim3(32, 24), 256, 0, stream>>>(
      xb, wqkvb, bqkv, 3072, 1024, 1024, nullptr, nullptr, nullptr, qbuf, kbuf, vbuf);
  // V -> V^T (coalesced LDS transpose)
  transpose_v_kernel<<<dim3(LSEQ / 64, NB * NHD), 256, 0, stream>>>(vbuf, vtbuf);
  // flash attention -> ao (L*B, C) bf16
  attn_kernel<<<dim3(LSEQ / 64, NHD, NB), 256, 0, stream>>>(qbuf, kbuf, vtbuf, ao);
  // out projection (M=4096, N=1024, K=1024) -> yz fp32
  gemm_bt<1, false, 64><<<dim3(32, 16), 256, 0, stream>>>(
      ao, woutb, bout, 1024, 1024, 1024, yz, nullptr, nullptr, nullptr, nullptr, nullptr);
  // LN1: x + yz -> x1f fp32, x1p bf16 (shifted +8 rows for l-padding)
  ln_kernel<<<MROWS, 256, 0, stream>>>(x, yz, nullptr, nullptr, n1w, n1b, x1f, x1p + 8 * 1024);
  // conv1 as 256x256 fused-phase GEMM (M=4096, N=4096, K=9216) + bias + relu -> hbuf bf16
  gemm256_conv1<<<dim3(16, 16), 512, 0, stream>>>(x1p, w1p, b1, hbuf);
  // conv2 pointwise (M=4096, N=1024, K=4096) split-K x2 -> yz, yzB (raw, bias in LN2)
  gemm_bt<1, false, 64><<<dim3(32, 16, 2), 256, 0, stream>>>(
      hbuf, w2b, nullptr, 1024, FFC, 2048, yz, yzB, nullptr, nullptr, nullptr, nullptr);
  // LN2: x1f + yz + yzB + b2 -> out fp32
  ln_kernel<<<MROWS, 256, 0, stream>>>(x1f, yz, yzB, b2, n2w, n2b, out, nullptr);
}

// Round 6
// 827.958 us; speedup vs baseline: 1.0341x; 1.0069x over previous
//
#include <hip/hip_runtime.h>
#include <cstdint>
#include <cstddef>

// Problem constants
#define LSEQ 2048
#define NB   2      // batch
#define CCH  1024   // channels
#define NHD  16     // heads
#define HDD  64     // head dim
#define FFC  4096   // conv hidden
#define KW   9      // conv kernel width
#define MROWS 4096  // L*B

typedef __bf16 bf16x8 __attribute__((ext_vector_type(8)));
typedef float  floatx4 __attribute__((ext_vector_type(4)));
typedef unsigned short ushort4v __attribute__((ext_vector_type(4)));

__device__ inline unsigned short f2bf(float f) {
  union { float f; unsigned u; } v; v.f = f;
  unsigned r = v.u + 0x7FFFu + ((v.u >> 16) & 1u);
  return (unsigned short)(r >> 16);
}

// async global->LDS, 16B per lane. Dest must be wave-uniform base + lane*16.
__device__ inline void gload_lds16(const unsigned short* g, unsigned short* l) {
  __builtin_amdgcn_global_load_lds(
      (__attribute__((address_space(1))) unsigned int*)(g),
      (__attribute__((address_space(3))) unsigned int*)(l), 16, 0, 0);
}

// ---------------- element-wise converts ----------------
__global__ void f2bf4_kernel(const float* __restrict__ in, unsigned short* __restrict__ out, int n4) {
  int idx = blockIdx.x * 256 + threadIdx.x;
  if (idx >= n4) return;
  const floatx4 v = ((const floatx4*)in)[idx];
  unsigned long long pk = (unsigned long long)f2bf(v[0]) |
                          ((unsigned long long)f2bf(v[1]) << 16) |
                          ((unsigned long long)f2bf(v[2]) << 32) |
                          ((unsigned long long)f2bf(v[3]) << 48);
  ((unsigned long long*)out)[idx] = pk;
}

// conv1_w (FF, C, K) fp32 -> w1p[f*9216 + k*1024 + c] bf16.
__global__ __launch_bounds__(256) void repack_w1_kernel(const float* __restrict__ in,
                                                        unsigned short* __restrict__ out) {
  __shared__ unsigned short t[9216];
  const int f = blockIdx.x, tid = threadIdx.x;
  const float* src = in + (size_t)f * 9216;
#pragma unroll
  for (int rnd = 0; rnd < 9; ++rnd) {
    const int p = (rnd * 256 + tid) * 4;
    const floatx4 v = *(const floatx4*)(src + p);
#pragma unroll
    for (int e = 0; e < 4; ++e) {
      const int idx = p + e;
      const int c = idx / 9, k = idx - c * 9;
      t[k * 1024 + c] = f2bf(v[e]);
    }
  }
  __syncthreads();
  unsigned short* dst = out + (size_t)f * 9216;
#pragma unroll
  for (int rnd = 0; rnd < 9; ++rnd) {
    const int j = (rnd * 256 + tid) * 4;
    *(ushort4v*)(dst + j) = *(const ushort4v*)&t[j];
  }
}

__global__ void zero_u16(unsigned short* p, int n) {
  int idx = blockIdx.x * 256 + threadIdx.x;
  if (idx < n) p[idx] = 0;
}

// V [bh][l][d] -> V^T [bh][d][l].  64x64 tile per block, LDS transpose,
// coalesced 8B on both sides.
__global__ __launch_bounds__(256) void transpose_v_kernel(
    const unsigned short* __restrict__ vin, unsigned short* __restrict__ vout) {
  __shared__ unsigned short t[64][65];
  const int tid = threadIdx.x;
  const int l0 = blockIdx.x * 64, bh = blockIdx.y;
  const unsigned short* src = vin + ((size_t)bh * LSEQ + l0) * HDD;
  const int rr = tid >> 4, cc = (tid & 15) * 4;
#pragma unroll
  for (int rnd = 0; rnd < 4; ++rnd) {
    const int row = rnd * 16 + rr;
    const ushort4v v = *(const ushort4v*)(src + row * HDD + cc);
#pragma unroll
    for (int e = 0; e < 4; ++e) t[row][cc + e] = v[e];
  }
  __syncthreads();
  unsigned short* dst = vout + (size_t)bh * HDD * LSEQ + l0;
#pragma unroll
  for (int rnd = 0; rnd < 4; ++rnd) {
    const int drow = rnd * 16 + rr;
    ushort4v v;
#pragma unroll
    for (int e = 0; e < 4; ++e) v[e] = t[cc + e][drow];
    *(ushort4v*)(dst + (size_t)drow * LSEQ + cc) = v;
  }
}

// ---------------- GEMM: C = A(MxK) * B(NxK)^T + bias ----------------
// 128xBN tile, BK=32, 4 waves, 16x16x32 bf16 MFMA, global_load_lds width=16,
// XOR swizzle (0 conflicts).  Used for QKV / out-proj / conv2.
template <int EPI, bool KDEC, int BN>
__global__ __launch_bounds__(256) void gemm_bt(
    const unsigned short* __restrict__ A, const unsigned short* __restrict__ Bm,
    const float* __restrict__ bias, int N, int Kstride, int Klen,
    float* __restrict__ outF, float* __restrict__ outF2,
    unsigned short* __restrict__ outB,
    unsigned short* __restrict__ qb, unsigned short* __restrict__ kb,
    unsigned short* __restrict__ vb) {
  constexpr int JN = BN / 32;  // j-fragments per wave
  __shared__ alignas(16) unsigned short lA[128 * 32];
  __shared__ alignas(16) unsigned short lB[BN * 32];
  const int tid = threadIdx.x;
  const int m0 = blockIdx.x * 128;
  const int n0 = blockIdx.y * BN;
  const int z = blockIdx.z;
  A += (size_t)z * Klen;
  Bm += (size_t)z * Klen;
  const int wave = tid >> 6, lane = tid & 63;
  const int wm = (wave >> 1) * 64, wn = (wave & 1) * (BN / 2);
  const int l16 = lane & 15, quad = lane >> 4;
  const int fsw = (quad ^ ((l16 >> 1) & 3)) << 3;

  size_t aoff[2], boff[BN / 64];
#pragma unroll
  for (int i = 0; i < 2; ++i) {
    const int cf = i * 256 + tid;
    const int row = cf >> 2, cs = cf & 3;
    const int col = ((cs ^ ((row >> 1) & 3)) << 3);
    aoff[i] = (KDEC ? (size_t)row * 1024 : (size_t)(m0 + row) * Kstride) + col;
  }
#pragma unroll
  for (int i = 0; i < BN / 64; ++i) {
    const int cf = i * 256 + tid;
    const int row = cf >> 2, cs = cf & 3;
    const int col = ((cs ^ ((row >> 1) & 3)) << 3);
    boff[i] = (size_t)(n0 + row) * Kstride + col;
  }

  floatx4 acc[4][JN];
#pragma unroll
  for (int i = 0; i < 4; ++i)
#pragma unroll
    for (int j = 0; j < JN; ++j) acc[i][j] = (floatx4){0.f, 0.f, 0.f, 0.f};

  auto kstep = [&](const unsigned short* Ab, const unsigned short* Bb) {
    __syncthreads();
#pragma unroll
    for (int i = 0; i < 2; ++i)
      gload_lds16(Ab + aoff[i], &lA[(i * 256 + tid) * 8]);
#pragma unroll
    for (int i = 0; i < BN / 64; ++i)
      gload_lds16(Bb + boff[i], &lB[(i * 256 + tid) * 8]);
    __syncthreads();
    bf16x8 af[4], bf[JN];
#pragma unroll
    for (int i = 0; i < 4; ++i)
      af[i] = *(const bf16x8*)&lA[(wm + i * 16 + l16) * 32 + fsw];
#pragma unroll
    for (int j = 0; j < JN; ++j)
      bf[j] = *(const bf16x8*)&lB[(wn + j * 16 + l16) * 32 + fsw];
#pragma unroll
    for (int i = 0; i < 4; ++i)
#pragma unroll
      for (int j = 0; j < JN; ++j)
        acc[i][j] = __builtin_amdgcn_mfma_f32_16x16x32_bf16(af[i], bf[j], acc[i][j], 0, 0, 0);
  };

  if (KDEC) {
    for (int seg = 0; seg < KW; ++seg) {
      const unsigned short* Ab = A + (size_t)(m0 + seg * NB) * 1024;
      const unsigned short* Bb = Bm + seg * 1024;
      for (int kk = 0; kk < 1024; kk += 32) kstep(Ab + kk, Bb + kk);
    }
  } else {
    for (int k0 = 0; k0 < Klen; k0 += 32) kstep(A + k0, Bm + k0);
  }

  float* outZ = (z == 0) ? outF : outF2;
#pragma unroll
  for (int i = 0; i < 4; ++i) {
#pragma unroll
    for (int j = 0; j < JN; ++j) {
      const int colg = n0 + wn + j * 16 + l16;
      const int rbase = m0 + wm + i * 16 + quad * 4;
      const float bv = bias ? bias[colg] : 0.f;
      float vv[4];
#pragma unroll
      for (int r = 0; r < 4; ++r) vv[r] = acc[i][j][r] + bv;
      if (EPI == 1) {
#pragma unroll
        for (int r = 0; r < 4; ++r) outZ[(size_t)(rbase + r) * N + colg] = vv[r];
      } else if (EPI == 2) {
#pragma unroll
        for (int r = 0; r < 4; ++r)
          outB[(size_t)(rbase + r) * N + colg] = f2bf(fmaxf(vv[r], 0.f));
      } else {
        const int seg = colg >> 10;  // 0:q 1:k 2:v
        const int c = colg & 1023, h = c >> 6, d = c & 63;
        unsigned short* dst = (seg == 0) ? qb : (seg == 1) ? kb : vb;
        const float scl = (seg == 0) ? 0.125f : 1.f;
#pragma unroll
        for (int r = 0; r < 4; ++r) {
          const int row = rbase + r, l = row >> 1, b = row & 1;
          dst[(((size_t)(b * NHD + h)) * LSEQ + l) * HDD + d] = f2bf(vv[r] * scl);
        }
      }
    }
  }
}

// ------- conv1 as 256x256 GEMM, register-pipelined phases (m201-style) ----
// out[m][f] = relu( sum_{seg,c} x1p[(m+seg*2)*1024+c] * w1p[f*9216+seg*1024+c] + b1[f] )
// M=N=4096, K=9216 (144 K-tiles of BK=64 = 288 khalf phases of K=32).
// 8 waves (2Mx4N), 512 thr.  LDS 128 KiB: 4 regions/matrix (2 buf x 2 khalf,
// 8KB each), region rg = (tile&1)*2 + kh.
//
// R5 finding: phase(2400cy) = MFMA(1242) + LDS(1150) IN SUM — zero overlap,
// because each wave's reads precede its dependent MFMAs and all waves are
// barrier-locked.  Fix = one-phase-ahead REGISTER pipelining (m201's actual
// mechanism): (bfc,af0) for phase p+1 are ds_read DURING phase p's MFMA
// clusters; phase p's cluster1 consumes registers loaded at p-1, so the LDS
// service of p+1's reads overlaps p's matrix work.  af1 is read in-phase
// (gated before cluster2 by the compiler's per-operand lgkmcnt) to cap peak
// fragment liveness at 64 VGPR (full 96-reg pipelining would breach the
// 256-reg 2-wave/SIMD cap and spill).
//
// Phase p body:
//   af1_p reads (4 b128) + stage S_p (4 gload_lds) ; sched_barrier
//   cluster1: af0_p x bfc_p   [16 MFMA; operands in regs since p-1]
//   pf: read (bfc,af0)_{p+1} from region R_{p+1} (8 b128) ; sched_barrier
//   cluster2: af1_p x bfc_p   [16 MFMA]
//   s_waitcnt vmcnt(N) ; s_barrier
// Compiler auto-inserts counted lgkmcnt before each MFMA use (m97-proven),
// draining pf_p before cluster1 and af1_p before cluster2 — hence every
// ds_read of region R_p completes before barrier p, and the stage at p+1
// that overwrites R_p is safe (no trailing lgkmcnt(0) needed).
// Stage cadence: S_p targets R_{p+3} (tiles T+1..T+3 alternating, as before).
// vmcnt TIGHTENED 8->4: S_p now drains per-wave by vmcnt(4) at end of p+1,
// workgroup-confirmed by barrier p+1, so the pf read of R_{p+3} at p+2 is
// race-free (with vmcnt(8) it would NOT be — stage loads could still be in
// flight).  Prologue vmcnt likewise 8->4 so pf@ph0 (region rg1) is covered.
// Latency slack: vmcnt(4) waits loads issued >= 1 full phase earlier
// (~1400cy > 900cy HBM miss).  Tail: stages end at phase 284; end-waits
// de-rate vmcnt(4)->vmcnt(0); final phase has no pf.
#define WV4 "s_waitcnt vmcnt(4)"
#define WV0 "s_waitcnt vmcnt(0)"
#define WNO "s_nop 0"
#define NOSTAGE ((void)0)

// read the pipelined fragment set (bfc + af0) of region rg into AA/BB
#define RDPF(AA, BB, rg) do {                                                  \
    const unsigned short* Pa_ = &lA[(rg) * 8192];                              \
    const unsigned short* Pb_ = &lB[(rg) * 8192];                              \
    _Pragma("unroll")                                                          \
    for (int j_ = 0; j_ < 4; ++j_)                                             \
      BB[j_] = *(const bf16x8*)&Pb_[(wn * 64 + j_ * 16 + l16) * 32 + fsw];     \
    _Pragma("unroll")                                                          \
    for (int i_ = 0; i_ < 4; ++i_)                                             \
      AA[i_] = *(const bf16x8*)&Pa_[(wm * 128 + i_ * 16 + l16) * 32 + fsw];    \
  } while (0)

#define PHASE(rg, CA, CB, DO_PF, STA, STB, WAITSTR) do {                       \
    asm volatile("" ::: "memory");                                             \
    const unsigned short* Ar_ = &lA[(rg) * 8192];                              \
    bf16x8 af1_[4];                                                            \
    _Pragma("unroll")                                                          \
    for (int i_ = 0; i_ < 4; ++i_)                                             \
      af1_[i_] = *(const bf16x8*)&Ar_[(wm * 128 + 64 + i_ * 16 + l16) * 32 + fsw]; \
    STA;                                                                       \
    STB;                                                                       \
    __builtin_amdgcn_sched_barrier(0);                                         \
    __builtin_amdgcn_s_setprio(1);                                             \
    _Pragma("unroll")                                                          \
    for (int i_ = 0; i_ < 4; ++i_)                                             \
      _Pragma("unroll")                                                        \
      for (int j_ = 0; j_ < 4; ++j_)                                           \
        acc[i_][j_] = __builtin_amdgcn_mfma_f32_16x16x32_bf16(                 \
            CA[i_], CB[j_], acc[i_][j_], 0, 0, 0);                             \
    __builtin_amdgcn_s_setprio(0);                                             \
    DO_PF;                                                                     \
    __builtin_amdgcn_sched_barrier(0);                                         \
    __builtin_amdgcn_s_setprio(1);                                             \
    _Pragma("unroll")                                                          \
    for (int i_ = 0; i_ < 4; ++i_)                                             \
      _Pragma("unroll")                                                        \
      for (int j_ = 0; j_ < 4; ++j_)                                           \
        acc[4 + i_][j_] = __builtin_amdgcn_mfma_f32_16x16x32_bf16(             \
            af1_[i_], CB[j_], acc[4 + i_][j_], 0, 0, 0);                       \
    __builtin_amdgcn_s_setprio(0);                                             \
    asm volatile(WAITSTR ::: "memory");                                        \
    __builtin_amdgcn_s_barrier();                                              \
  } while (0)

__global__ __launch_bounds__(512, 2) void gemm256_conv1(
    const unsigned short* __restrict__ A,   // x1p base (4112 rows x 1024)
    const unsigned short* __restrict__ Bm,  // w1p (4096 x 9216)
    const float* __restrict__ bias,         // b1
    unsigned short* __restrict__ outB) {    // hbuf (4096 x 4096)
  __shared__ alignas(16) unsigned short lA[4 * 8192];  // [buf][kh][256][32]
  __shared__ alignas(16) unsigned short lB[4 * 8192];
  const int tid = threadIdx.x;
  const int m0 = blockIdx.x * 256, n0 = blockIdx.y * 256;
  const int wave = tid >> 6, lane = tid & 63;
  const int wm = wave >> 2, wn = wave & 3;        // 2 x 4 wave grid
  const int l16 = lane & 15, quad = lane >> 4;
  const int fsw = (quad ^ ((l16 >> 1) & 3)) << 3;

  // per-thread staging base offsets (elements), swizzled col
  unsigned int aoff[2], boff[2];
#pragma unroll
  for (int i = 0; i < 2; ++i) {
    const int cf = i * 512 + tid;
    const int row = cf >> 2, cs = cf & 3;
    const int col = (cs ^ ((row >> 1) & 3)) << 3;
    aoff[i] = (unsigned)(m0 + row) * 1024u + (unsigned)col;
    boff[i] = (unsigned)(n0 + row) * 9216u + (unsigned)col;
  }

  floatx4 acc[8][4];
#pragma unroll
  for (int i = 0; i < 8; ++i)
#pragma unroll
    for (int j = 0; j < 4; ++j) acc[i][j] = (floatx4){0.f, 0.f, 0.f, 0.f};

  // two alternating pipelined fragment sets (static names — rule #20)
  bf16x8 pa0[4], pb0[4], pa1[4], pb1[4];

  // stage one khalf region (2 x global_load_lds dwordx4 per thread)
  auto stA = [&](int t, int kh) {
    const int p = t & 1;
    const unsigned koff = (unsigned)(t >> 4) * 2048u + (unsigned)((t & 15) * 64 + kh * 32);
#pragma unroll
    for (int i = 0; i < 2; ++i)
      gload_lds16(A + aoff[i] + koff, &lA[(p * 2 + kh) * 8192 + (i * 512 + tid) * 8]);
  };
  auto stB = [&](int t, int kh) {
    const int p = t & 1;
    const unsigned koff = (unsigned)t * 64u + (unsigned)(kh * 32);
#pragma unroll
    for (int i = 0; i < 2; ++i)
      gload_lds16(Bm + boff[i] + koff, &lB[(p * 2 + kh) * 8192 + (i * 512 + tid) * 8]);
  };

  // prologue: tile0 (both khalves) + tile1 kh0 = 12 loads; drain first 8
  // (regions rg0, rg1) so pf@ph0 (rg1 read) is race-free; then prime set0
  // with rg0's (bfc, af0).
  stA(0, 0); stB(0, 0); stA(0, 1); stB(0, 1); stA(1, 0); stB(1, 0);
  asm volatile("s_waitcnt vmcnt(4)" ::: "memory");
  __builtin_amdgcn_s_barrier();
  RDPF(pa0, pb0, 0);

  const int NIT = 72;  // 144 K-tiles / 2 per iteration (4 phases each)
  for (int it = 0; it < NIT - 1; ++it) {
    const int T = it * 2;
    PHASE(0, pa0, pb0, RDPF(pa1, pb1, 1), stA(T + 1, 1), stB(T + 1, 1), WV4);
    PHASE(1, pa1, pb1, RDPF(pa0, pb0, 2), stA(T + 2, 0), stB(T + 2, 0), WV4);
    PHASE(2, pa0, pb0, RDPF(pa1, pb1, 3), stA(T + 2, 1), stB(T + 2, 1), WV4);
    PHASE(3, pa1, pb1, RDPF(pa0, pb0, 0), stA(T + 3, 0), stB(T + 3, 0), WV4);
  }
  {  // last iteration (tiles 142,143): stages end at first phase; de-rate
    PHASE(0, pa0, pb0, RDPF(pa1, pb1, 1), stA(143, 1), stB(143, 1), WV4);
    PHASE(1, pa1, pb1, RDPF(pa0, pb0, 2), NOSTAGE, NOSTAGE, WV0);
    PHASE(2, pa0, pb0, RDPF(pa1, pb1, 3), NOSTAGE, NOSTAGE, WV0);
    PHASE(3, pa1, pb1, NOSTAGE, NOSTAGE, NOSTAGE, WNO);
  }

  // epilogue: row = m0 + wm*128 + ii*16 + quad*4 + r, col = n0 + wn*64 + j*16 + l16
#pragma unroll
  for (int ii = 0; ii < 8; ++ii) {
#pragma unroll
    for (int j = 0; j < 4; ++j) {
      const int colg = n0 + wn * 64 + j * 16 + l16;
      const int rbase = m0 + wm * 128 + ii * 16 + quad * 4;
      const float bv = bias[colg];
#pragma unroll
      for (int r = 0; r < 4; ++r)
        outB[(size_t)(rbase + r) * FFC + colg] = f2bf(fmaxf(acc[ii][j][r] + bv, 0.f));
    }
  }
}

// ---------------- flash attention ----------------
__global__ __launch_bounds__(256) void attn_kernel(
    const unsigned short* __restrict__ qg, const unsigned short* __restrict__ kg,
    const unsigned short* __restrict__ vtg, unsigned short* __restrict__ ao) {
  __shared__ alignas(16) unsigned short lK[64 * 64];   // [key][d] swizzled
  __shared__ alignas(16) unsigned short lV[64 * 64];   // [d][key] swizzled
  __shared__ alignas(16) unsigned short lP[4][16 * 64];
  const int tid = threadIdx.x;
  const int wave = tid >> 6, lane = tid & 63;
  const int l16 = lane & 15, quad = lane >> 4;
  const int sw0 = ((quad ^ (l16 & 7)) << 3);
  const int sw1 = (((quad | 4) ^ (l16 & 7)) << 3);
  const int qt = blockIdx.x, h = blockIdx.y, b = blockIdx.z;
  const unsigned short* Q = qg + ((size_t)(b * NHD + h) * LSEQ) * HDD;
  const unsigned short* Kp = kg + ((size_t)(b * NHD + h) * LSEQ) * HDD;
  const unsigned short* Vt = vtg + ((size_t)(b * NHD + h) * HDD) * LSEQ;
  const int q0 = qt * 64 + wave * 16;

  const bf16x8 qa0 = *(const bf16x8*)&Q[(size_t)(q0 + l16) * HDD + quad * 8];
  const bf16x8 qa1 = *(const bf16x8*)&Q[(size_t)(q0 + l16) * HDD + 32 + quad * 8];

  float mr[4], lr[4];
  floatx4 o[4];
#pragma unroll
  for (int r = 0; r < 4; ++r) { mr[r] = -1e30f; lr[r] = 0.f; }
#pragma unroll
  for (int nb = 0; nb < 4; ++nb) o[nb] = (floatx4){0.f, 0.f, 0.f, 0.f};

  for (int kt = 0; kt < LSEQ; kt += 64) {
    __syncthreads();
#pragma unroll
    for (int i = 0; i < 2; ++i) {
      const int flat = i * 256 + tid;
      const int row = flat >> 3, cs = flat & 7;
      const int col = ((cs ^ (row & 7)) << 3);
      gload_lds16(&Kp[(size_t)(kt + row) * HDD + col], &lK[flat * 8]);
      gload_lds16(&Vt[(size_t)row * LSEQ + kt + col], &lV[flat * 8]);
    }
    __syncthreads();
    floatx4 s[4];
#pragma unroll
    for (int nb = 0; nb < 4; ++nb) {
      const bf16x8 kf0 = *(const bf16x8*)&lK[(nb * 16 + l16) * 64 + sw0];
      const bf16x8 kf1 = *(const bf16x8*)&lK[(nb * 16 + l16) * 64 + sw1];
      floatx4 t = (floatx4){0.f, 0.f, 0.f, 0.f};
      t = __builtin_amdgcn_mfma_f32_16x16x32_bf16(qa0, kf0, t, 0, 0, 0);
      t = __builtin_amdgcn_mfma_f32_16x16x32_bf16(qa1, kf1, t, 0, 0, 0);
      s[nb] = t;
    }
    float mnew[4], alpha[4];
#pragma unroll
    for (int r = 0; r < 4; ++r) {
      float mx = fmaxf(fmaxf(s[0][r], s[1][r]), fmaxf(s[2][r], s[3][r]));
      mx = fmaxf(mx, __shfl_xor(mx, 1));
      mx = fmaxf(mx, __shfl_xor(mx, 2));
      mx = fmaxf(mx, __shfl_xor(mx, 4));
      mx = fmaxf(mx, __shfl_xor(mx, 8));
      mnew[r] = fmaxf(mr[r], mx);
      alpha[r] = __expf(mr[r] - mnew[r]);
      mr[r] = mnew[r];
    }
#pragma unroll
    for (int nb = 0; nb < 4; ++nb)
#pragma unroll
      for (int r = 0; r < 4; ++r) s[nb][r] = __expf(s[nb][r] - mnew[r]);
#pragma unroll
    for (int r = 0; r < 4; ++r) {
      float sm = s[0][r] + s[1][r] + s[2][r] + s[3][r];
      sm += __shfl_xor(sm, 1);
      sm += __shfl_xor(sm, 2);
      sm += __shfl_xor(sm, 4);
      sm += __shfl_xor(sm, 8);
      lr[r] = lr[r] * alpha[r] + sm;
    }
#pragma unroll
    for (int nb = 0; nb < 4; ++nb)
#pragma unroll
      for (int r = 0; r < 4; ++r) {
        const int row = quad * 4 + r;
        const int q = nb * 2 + (l16 >> 3);
        lP[wave][row * 64 + ((q ^ (row & 7)) << 3) + (l16 & 7)] = f2bf(s[nb][r]);
        o[nb][r] *= alpha[r];
      }
    asm volatile("s_waitcnt lgkmcnt(0)" ::: "memory");
    const bf16x8 pa0 = *(const bf16x8*)&lP[wave][l16 * 64 + sw0];
    const bf16x8 pa1 = *(const bf16x8*)&lP[wave][l16 * 64 + sw1];
#pragma unroll
    for (int nb = 0; nb < 4; ++nb) {
      const bf16x8 vf0 = *(const bf16x8*)&lV[(nb * 16 + l16) * 64 + sw0];
      const bf16x8 vf1 = *(const bf16x8*)&lV[(nb * 16 + l16) * 64 + sw1];
      o[nb] = __builtin_amdgcn_mfma_f32_16x16x32_bf16(pa0, vf0, o[nb], 0, 0, 0);
      o[nb] = __builtin_amdgcn_mfma_f32_16x16x32_bf16(pa1, vf1, o[nb], 0, 0, 0);
    }
  }
#pragma unroll
  for (int nb = 0; nb < 4; ++nb)
#pragma unroll
    for (int r = 0; r < 4; ++r) {
      const float v = o[nb][r] / lr[r];
      const int lg = q0 + quad * 4 + r;
      ao[((size_t)lg * NB + b) * CCH + h * HDD + nb * 16 + l16] = f2bf(v);
    }
}

// ---------------- layernorm (+residuals) ----------------
__global__ __launch_bounds__(256) void ln_kernel(
    const float* __restrict__ a, const float* __restrict__ c,
    const float* __restrict__ c2, const float* __restrict__ cbias,
    const float* __restrict__ w, const float* __restrict__ bias,
    float* __restrict__ outF, unsigned short* __restrict__ outB) {
  const int row = blockIdx.x;
  const int tid = threadIdx.x;
  const floatx4 va = *(const floatx4*)(a + (size_t)row * 1024 + tid * 4);
  const floatx4 vc = *(const floatx4*)(c + (size_t)row * 1024 + tid * 4);
  float v0 = va[0] + vc[0], v1 = va[1] + vc[1], v2 = va[2] + vc[2], v3 = va[3] + vc[3];
  if (c2) {
    const floatx4 v2c = *(const floatx4*)(c2 + (size_t)row * 1024 + tid * 4);
    v0 += v2c[0]; v1 += v2c[1]; v2 += v2c[2]; v3 += v2c[3];
  }
  if (cbias) {
    const floatx4 vb = *(const floatx4*)(cbias + tid * 4);
    v0 += vb[0]; v1 += vb[1]; v2 += vb[2]; v3 += vb[3];
  }
  float s = v0 + v1 + v2 + v3;
  float ss = v0 * v0 + v1 * v1 + v2 * v2 + v3 * v3;
#pragma unroll
  for (int off = 1; off < 64; off <<= 1) {
    s += __shfl_xor(s, off);
    ss += __shfl_xor(ss, off);
  }
  __shared__ float red[8];
  const int wave = tid >> 6, lane = tid & 63;
  if (lane == 0) { red[wave] = s; red[4 + wave] = ss; }
  __syncthreads();
  s = red[0] + red[1] + red[2] + red[3];
  ss = red[4] + red[5] + red[6] + red[7];
  const float mu = s * (1.f / 1024.f);
  const float var = ss * (1.f / 1024.f) - mu * mu;
  const float rs = rsqrtf(var + 1e-5f);
  const floatx4 wv = *(const floatx4*)(w + tid * 4);
  const floatx4 bv = *(const floatx4*)(bias + tid * 4);
  const float o0 = (v0 - mu) * rs * wv[0] + bv[0];
  const float o1 = (v1 - mu) * rs * wv[1] + bv[1];
  const float o2 = (v2 - mu) * rs * wv[2] + bv[2];
  const float o3 = (v3 - mu) * rs * wv[3] + bv[3];
  *(floatx4*)(outF + (size_t)row * 1024 + tid * 4) = (floatx4){o0, o1, o2, o3};
  if (outB) {
    unsigned long long pk = (unsigned long long)f2bf(o0) |
                            ((unsigned long long)f2bf(o1) << 16) |
                            ((unsigned long long)f2bf(o2) << 32) |
                            ((unsigned long long)f2bf(o3) << 48);
    *(unsigned long long*)(outB + (size_t)row * 1024 + tid * 4) = pk;
  }
}

extern "C" void kernel_launch(void* const* d_in, const int* in_sizes, int n_in,
                              void* d_out, int out_size, void* d_ws, size_t ws_size,
                              hipStream_t stream) {
  const float* x = (const float*)d_in[0];
  const float* wqkv = (const float*)d_in[2];
  const float* bqkv = (const float*)d_in[3];
  const float* wout = (const float*)d_in[4];
  const float* bout = (const float*)d_in[5];
  const float* w1 = (const float*)d_in[6];
  const float* b1 = (const float*)d_in[7];
  const float* w2 = (const float*)d_in[8];
  const float* b2 = (const float*)d_in[9];
  const float* n1w = (const float*)d_in[10];
  const float* n1b = (const float*)d_in[11];
  const float* n2w = (const float*)d_in[12];
  const float* n2b = (const float*)d_in[13];
  float* out = (float*)d_out;

  char* ws = (char*)d_ws;
  size_t off = 0;
  auto alloc = [&](size_t bytes) -> char* {
    char* p = ws + off;
    off += (bytes + 255) & ~(size_t)255;
    return p;
  };
  unsigned short* xb    = (unsigned short*)alloc((size_t)MROWS * 1024 * 2);   // 8.4 MB
  unsigned short* wqkvb = (unsigned short*)alloc((size_t)3072 * 1024 * 2);    // 6.3 MB
  unsigned short* woutb = (unsigned short*)alloc((size_t)1024 * 1024 * 2);    // 2.1 MB
  unsigned short* w1p   = (unsigned short*)alloc((size_t)FFC * 9216 * 2);
  unsigned short* w2b   = (unsigned short*)alloc((size_t)1024 * FFC * 2);
  unsigned short* qbuf  = (unsigned short*)alloc((size_t)NB * NHD * LSEQ * HDD * 2);
  unsigned short* kbuf  = (unsigned short*)alloc((size_t)NB * NHD * LSEQ * HDD * 2);
  unsigned short* vtbuf = (unsigned short*)alloc((size_t)NB * NHD * LSEQ * HDD * 2);
  unsigned short* ao    = (unsigned short*)alloc((size_t)MROWS * 1024 * 2);
  float*          yz    = (float*)alloc((size_t)MROWS * 1024 * 4);
  float*          x1f   = (float*)alloc((size_t)MROWS * 1024 * 4);
  unsigned short* x1p   = (unsigned short*)alloc((size_t)(LSEQ + 8) * NB * 1024 * 2);
  unsigned short* hbuf  = (unsigned short*)alloc((size_t)MROWS * FFC * 2);
  if (off > ws_size) return;  // workspace too small -> visible failure
  // dead-region aliases (no extra ws):
  float*          yzB   = (float*)xb;
  unsigned short* vbuf  = hbuf;

  int n;
  n = MROWS * 1024 / 4; f2bf4_kernel<<<(n + 255) / 256, 256, 0, stream>>>(x, xb, n);
  n = 3072 * 1024 / 4;  f2bf4_kernel<<<(n + 255) / 256, 256, 0, stream>>>(wqkv, wqkvb, n);
  n = 1024 * 1024 / 4;  f2bf4_kernel<<<(n + 255) / 256, 256, 0, stream>>>(wout, woutb, n);
  n = 1024 * FFC / 4;   f2bf4_kernel<<<(n + 255) / 256, 256, 0, stream>>>(w2, w2b, n);
  repack_w1_kernel<<<FFC, 256, 0, stream>>>(w1, w1p);
  zero_u16<<<32, 256, 0, stream>>>(x1p, 8 * 1024);
  zero_u16<<<32, 256, 0, stream>>>(x1p + (size_t)(LSEQ + 4) * NB * 1024, 8 * 1024);

  // QKV projection (M=4096, N=3072, K=1024); q/k/v all natural [b,h,l,d]
  gemm_bt<0, false, 128><<<dim3(32, 24), 256, 0, stream>>>(
      xb, wqkvb, bqkv, 3072, 1024, 1024, nullptr, nullptr, nullptr, qbuf, kbuf, vbuf);
  // V -> V^T (coalesced LDS transpose)
  transpose_v_kernel<<<dim3(LSEQ / 64, NB * NHD), 256, 0, stream>>>(vbuf, vtbuf);
  // flash attention -> ao (L*B, C) bf16
  attn_kernel<<<dim3(LSEQ / 64, NHD, NB), 256, 0, stream>>>(qbuf, kbuf, vtbuf, ao);
  // out projection (M=4096, N=1024, K=1024) -> yz fp32
  gemm_bt<1, false, 64><<<dim3(32, 16), 256, 0, stream>>>(
      ao, woutb, bout, 1024, 1024, 1024, yz, nullptr, nullptr, nullptr, nullptr, nullptr);
  // LN1: x + yz -> x1f fp32, x1p bf16 (shifted +8 rows for l-padding)
  ln_kernel<<<MROWS, 256, 0, stream>>>(x, yz, nullptr, nullptr, n1w, n1b, x1f, x1p + 8 * 1024);
  // conv1 as 256x256 register-pipelined GEMM (M=4096, N=4096, K=9216) -> hbuf bf16
  gemm256_conv1<<<dim3(16, 16), 512, 0, stream>>>(x1p, w1p, b1, hbuf);
  // conv2 pointwise (M=4096, N=1024, K=4096) split-K x2 -> yz, yzB (raw, bias in LN2)
  gemm_bt<1, false, 64><<<dim3(32, 16, 2), 256, 0, stream>>>(
      hbuf, w2b, nullptr, 1024, FFC, 2048, yz, yzB, nullptr, nullptr, nullptr, nullptr);
  // LN2: x1f + yz + yzB + b2 -> out fp32
  ln_kernel<<<MROWS, 256, 0, stream>>>(x1f, yz, yzB, b2, n2w, n2b, out, nullptr);
}